// Round 1
// baseline (2196.977 us; speedup 1.0000x reference)
//
#include <hip/hip_runtime.h>
#include <math.h>

#define NB 4
#define NN 4096
#define NC 128
#define NROWS (NB*NN)
#define SCALE_F 0.08838834764831845f   // 1/sqrt(128)

__device__ __forceinline__ float rl_f(float x, int l) {
    return __int_as_float(__builtin_amdgcn_readlane(__float_as_int(x), l));
}

// ---------------- per-thread top-16 (registers only, static indexing) ----------------
struct Top16 {
    float v[16]; int id[16]; float wv; int wi;
    __device__ __forceinline__ void init() {
#pragma unroll
        for (int s = 0; s < 16; ++s) { v[s] = INFINITY; id[s] = 0x7fffffff; }
        wv = INFINITY; wi = 0x7fffffff;
    }
    // lexicographic (value, index) top-k, matching jax.lax.top_k tie-breaking.
    // stream is in increasing j, so strict-< plus (==, j<wi) is exact.
    __device__ __forceinline__ void insert(float d, int j) {
        if (d < wv || (d == wv && j < wi)) {
            bool done = false;
#pragma unroll
            for (int s = 0; s < 16; ++s) {
                if (!done && v[s] == wv && id[s] == wi) { v[s] = d; id[s] = j; done = true; }
            }
            float nwv = -INFINITY; int nwi = -1;
#pragma unroll
            for (int s = 0; s < 16; ++s) {
                if (v[s] > nwv || (v[s] == nwv && id[s] > nwi)) { nwv = v[s]; nwi = id[s]; }
            }
            wv = nwv; wi = nwi;
        }
    }
};

// ---------------- tiny weight combos ----------------
// Wkp0 = Wk0@Wp0 [128,3], bk0 = Wk0@bp0 ; same for V
__global__ void combo_small(const float* __restrict__ Wk0, const float* __restrict__ Wv0,
                            const float* __restrict__ Wp0, const float* __restrict__ bp0,
                            float* __restrict__ WKP0, float* __restrict__ BK0,
                            float* __restrict__ WVP0, float* __restrict__ BV0)
{
    int task = blockIdx.x * 512 + threadIdx.x;   // grid 2 x 512 = 1024
    if (task >= 1024) return;
    int mat = task >> 9; int rem = task & 511;
    int c = rem >> 2, t = rem & 3;
    const float* W = mat ? Wv0 : Wk0;
    float s = 0.f;
    if (t < 3) {
        for (int d = 0; d < 128; ++d) s = fmaf(W[c*128+d], Wp0[d*3+t], s);
        (mat ? WVP0 : WKP0)[c*3+t] = s;
    } else {
        for (int d = 0; d < 128; ++d) s = fmaf(W[c*128+d], bp0[d], s);
        (mat ? BV0 : BK0)[c] = s;
    }
}

// Mk1 = Wk1@Wp1 [128,128], bk1 = Wk1@bp1 ; same for V
__global__ void combo_big(const float* __restrict__ Wk1, const float* __restrict__ Wv1,
                          const float* __restrict__ Wp1, const float* __restrict__ bp1,
                          float* __restrict__ MK1, float* __restrict__ BK1,
                          float* __restrict__ MV1, float* __restrict__ BV1)
{
    int task = blockIdx.x * 256 + threadIdx.x;   // grid 129 x 256 = 33024
    if (task >= 33024) return;
    int mat = task >= 16512; int rem = mat ? task - 16512 : task;
    const float* W = mat ? Wv1 : Wk1;
    if (rem < 16384) {
        int c = rem >> 7, t = rem & 127;
        float s = 0.f;
        for (int d = 0; d < 128; ++d) s = fmaf(W[c*128+d], Wp1[d*128+t], s);
        (mat ? MV1 : MK1)[rem] = s;
    } else {
        int c = rem - 16384;
        float s = 0.f;
        for (int d = 0; d < 128; ++d) s = fmaf(W[c*128+d], bp1[d], s);
        (mat ? BV1 : BK1)[c] = s;
    }
}

// srcKp = src @ Wkp0^T, srcVp = src @ Wvp0^T   (K=3)
__global__ void srcproj(const float* __restrict__ src, const float* __restrict__ WKP0,
                        const float* __restrict__ WVP0,
                        float* __restrict__ srcKp, float* __restrict__ srcVp)
{
    int gid = blockIdx.x * 256 + threadIdx.x;    // grid 8192
    int i = gid >> 7, c = gid & 127;
    float s0 = src[i*3+0], s1 = src[i*3+1], s2 = src[i*3+2];
    srcKp[gid] = fmaf(s0, WKP0[c*3+0], fmaf(s1, WKP0[c*3+1], s2*WKP0[c*3+2]));
    srcVp[gid] = fmaf(s0, WVP0[c*3+0], fmaf(s1, WVP0[c*3+1], s2*WVP0[c*3+2]));
}

// ---------------- KNN stage 1 (3-D coords), one wave per row ----------------
__global__ __launch_bounds__(256) void knn1_kernel(const float* __restrict__ src,
                                                   int* __restrict__ idxout)
{
    int lane = threadIdx.x & 63, wave = threadIdx.x >> 6;
    int b7 = blockIdx.x & 7, sub = blockIdx.x >> 3;      // grid 4096
    int batch = b7 >> 1;
    int rib = (sub*2 + (b7 & 1))*4 + wave;
    int row = batch*NN + rib;
    const float* sb = src + batch*NN*3;
    float xi0 = sb[rib*3], xi1 = sb[rib*3+1], xi2 = sb[rib*3+2];
    Top16 top; top.init();
    for (int c0 = 0; c0 < NN; c0 += 64) {
        int j = c0 + lane;
        float dx = xi0 - sb[j*3], dy = xi1 - sb[j*3+1], dz = xi2 - sb[j*3+2];
        float d2 = fmaf(dx, dx, fmaf(dy, dy, dz*dz));
        top.insert(d2, j);
    }
    // wave merge: 16 rounds of global lexicographic min extraction
    for (int t = 0; t < 16; ++t) {
        float lv = INFINITY; int lid = 0x7fffffff;
#pragma unroll
        for (int s = 0; s < 16; ++s) {
            if (top.v[s] < lv || (top.v[s] == lv && top.id[s] < lid)) { lv = top.v[s]; lid = top.id[s]; }
        }
        float gv = lv; int gi = lid;
#pragma unroll
        for (int off = 1; off < 64; off <<= 1) {
            float ov = __shfl_xor(gv, off, 64);
            int oi = __shfl_xor(gi, off, 64);
            if (ov < gv || (ov == gv && oi < gi)) { gv = ov; gi = oi; }
        }
        if (lane == 0) idxout[row*16 + t] = gi;
        if (lv == gv && lid == gi) {
#pragma unroll
            for (int s = 0; s < 16; ++s) {
                if (top.v[s] == gv && top.id[s] == gi) { top.v[s] = INFINITY; top.id[s] = 0x7fffffff; }
            }
        }
    }
}

// ---------------- generic [M,128]@[128,128]^T matmul (Y = X @ W^T) ----------------
__global__ __launch_bounds__(256) void matmul128(const float* __restrict__ X,
                                                 const float* __restrict__ W,
                                                 float* __restrict__ Y)
{
    __shared__ float WL[128*128];   // WL[d][c^s(d)] = W[c][d], s(d)=d&14 (xor swizzle)
    int tid = threadIdx.x;
    for (int f = tid; f < 16384; f += 256) {
        int c = f >> 7, d = f & 127;
        WL[d*128 + (c ^ (d & 14))] = W[f];
    }
    __syncthreads();
    int lane = tid & 63, wave = tid >> 6;
#pragma unroll
    for (int it = 0; it < 2; ++it) {                  // grid 512 x 32 rows
        int row0 = blockIdx.x*32 + it*16 + wave*4;
        float x0[4], x1[4];
#pragma unroll
        for (int r = 0; r < 4; ++r) {
            x0[r] = X[(row0+r)*128 + lane];
            x1[r] = X[(row0+r)*128 + lane + 64];
        }
        float2 acc[4];
#pragma unroll
        for (int r = 0; r < 4; ++r) { acc[r].x = 0.f; acc[r].y = 0.f; }
#pragma unroll 8
        for (int d = 0; d < 64; ++d) {
            int cidx = (2*lane) ^ (d & 14);           // (d+64)&14 == d&14
            float2 wa = *(const float2*)&WL[d*128 + cidx];
            float2 wb = *(const float2*)&WL[(d+64)*128 + cidx];
#pragma unroll
            for (int r = 0; r < 4; ++r) {
                float xa = rl_f(x0[r], d);
                float xb = rl_f(x1[r], d);
                acc[r].x = fmaf(xa, wa.x, acc[r].x);
                acc[r].y = fmaf(xa, wa.y, acc[r].y);
                acc[r].x = fmaf(xb, wb.x, acc[r].x);
                acc[r].y = fmaf(xb, wb.y, acc[r].y);
            }
        }
#pragma unroll
        for (int r = 0; r < 4; ++r) {
            *(float2*)&Y[(row0+r)*128 + 2*lane] = acc[r];
        }
    }
}

// ---------------- gather attention (shared by both stages) ----------------
// K_k = RK[i] - RK[j] + GK[j] + bk ; V_k = RV[i] - RV[j] + GV[j] + bv
__global__ __launch_bounds__(256) void attn_kernel(
    const float* __restrict__ Q,  const float* __restrict__ RK, const float* __restrict__ GK,
    const float* __restrict__ RV, const float* __restrict__ GV,
    const float* __restrict__ bk, const float* __restrict__ bv,
    const int* __restrict__ idx, float* __restrict__ outp, float* __restrict__ x2out)
{
    int lane = threadIdx.x & 63, wave = threadIdx.x >> 6;
    int b7 = blockIdx.x & 7, sub = blockIdx.x >> 3;      // grid 4096, XCD-batch affinity
    int batch = b7 >> 1;
    int rib = (sub*2 + (b7 & 1))*4 + wave;
    int row = batch*NN + rib;
    const float* RKb = RK + (size_t)batch*NN*NC;
    const float* GKb = GK + (size_t)batch*NN*NC;
    const float* RVb = RV + (size_t)batch*NN*NC;
    const float* GVb = GV + (size_t)batch*NN*NC;

    float q0 = Q[row*NC + lane], q1 = Q[row*NC + lane + 64];
    float rki0 = RKb[rib*NC + lane], rki1 = RKb[rib*NC + lane + 64];
    float rvi0 = RVb[rib*NC + lane], rvi1 = RVb[rib*NC + lane + 64];
    float bka = bk[lane], bkb = bk[lane+64];
    float bva = bv[lane], bvb = bv[lane+64];

    int jarr[16];
#pragma unroll
    for (int k = 0; k < 16; ++k) jarr[k] = idx[row*16 + k];

    float sc[16];
#pragma unroll
    for (int k = 0; k < 16; ++k) {
        int j = jarr[k];
        float kk0 = rki0 - RKb[j*NC + lane]      + GKb[j*NC + lane]      + bka;
        float kk1 = rki1 - RKb[j*NC + lane + 64] + GKb[j*NC + lane + 64] + bkb;
        float p = fmaf(q0, kk0, q1*kk1);
#pragma unroll
        for (int off = 1; off < 64; off <<= 1) p += __shfl_xor(p, off, 64);
        sc[k] = p * SCALE_F;
    }
    float m = sc[0];
#pragma unroll
    for (int k = 1; k < 16; ++k) m = fmaxf(m, sc[k]);
    float wsum = 0.f, w[16];
#pragma unroll
    for (int k = 0; k < 16; ++k) { w[k] = expf(sc[k] - m); wsum += w[k]; }
    float inv = 1.f / wsum;
    float a0 = 0.f, a1 = 0.f;
#pragma unroll
    for (int k = 0; k < 16; ++k) {
        int j = jarr[k];
        float a = w[k] * inv;
        float vv0 = rvi0 - RVb[j*NC + lane]      + GVb[j*NC + lane]      + bva;
        float vv1 = rvi1 - RVb[j*NC + lane + 64] + GVb[j*NC + lane + 64] + bvb;
        a0 = fmaf(a, vv0, a0);
        a1 = fmaf(a, vv1, a1);
    }
    outp[row*NC + lane]      = a0;
    outp[row*NC + lane + 64] = a1;
    if (x2out != nullptr) {                         // squared norm for feature-space KNN
        float x2 = fmaf(a0, a0, a1*a1);
#pragma unroll
        for (int off = 1; off < 64; off <<= 1) x2 += __shfl_xor(x2, off, 64);
        if (lane == 0) x2out[row] = x2;
    }
}

// ---------------- KNN stage 2 (128-D features), fused Gram-tile + top-16 ----------------
__global__ __launch_bounds__(256) void knn2_kernel(const float* __restrict__ X,
                                                   const float* __restrict__ x2g,
                                                   int* __restrict__ idxout)
{
    __shared__ float XRT[128*64];   // [d][r]       32.0 KB  (rows of the band, transposed)
    __shared__ float XCT[128*34];   // [d][c] pad34 17.4 KB  (current col tile, transposed)
    __shared__ float DT[64*33];     // [r][c] pad33  8.4 KB  (dot tile)
    __shared__ float X2C[32];
    int tid = threadIdx.x;
    int xcd = blockIdx.x & 7, sub = blockIdx.x >> 3;     // grid 256; XCD owns one batch
    int batch = xcd >> 1;
    int rowblk = sub*2 + (xcd & 1);                      // 0..63
    const float* Xb  = X   + (size_t)batch*NN*NC;
    const float* x2b = x2g + (size_t)batch*NN;
    int r0 = rowblk*64;

    for (int f4 = tid; f4 < 64*32; f4 += 256) {          // stage row band transposed
        int r = f4 >> 5, d4 = f4 & 31;
        float4 g = *(const float4*)&Xb[(r0 + r)*NC + d4*4];
        XRT[(d4*4+0)*64 + r] = g.x;
        XRT[(d4*4+1)*64 + r] = g.y;
        XRT[(d4*4+2)*64 + r] = g.z;
        XRT[(d4*4+3)*64 + r] = g.w;
    }

    int rg = tid >> 4;                                   // 0..15 -> rows rg*4..+3
    int cg = tid & 15;                                   // cols cg*2, cg*2+1
    int ownRow = (cg < 4) ? (rg*4 + cg) : -1;            // 64 owners, 16 per wave
    Top16 top; top.init();

    for (int c0 = 0; c0 < NN; c0 += 32) {
        __syncthreads();                                 // prev scan done before restage
        for (int f4 = tid; f4 < 32*32; f4 += 256) {
            int c = f4 >> 5, d4 = f4 & 31;
            float4 g = *(const float4*)&Xb[(c0 + c)*NC + d4*4];
            XCT[(d4*4+0)*34 + c] = g.x;
            XCT[(d4*4+1)*34 + c] = g.y;
            XCT[(d4*4+2)*34 + c] = g.z;
            XCT[(d4*4+3)*34 + c] = g.w;
        }
        if (tid < 32) X2C[tid] = x2b[c0 + tid];
        __syncthreads();

        float acc00=0,acc01=0,acc10=0,acc11=0,acc20=0,acc21=0,acc30=0,acc31=0;
#pragma unroll 16
        for (int d = 0; d < 128; ++d) {
            float4 xr = *(const float4*)&XRT[d*64 + rg*4];
            float2 xc = *(const float2*)&XCT[d*34 + cg*2];
            acc00 = fmaf(xr.x, xc.x, acc00); acc01 = fmaf(xr.x, xc.y, acc01);
            acc10 = fmaf(xr.y, xc.x, acc10); acc11 = fmaf(xr.y, xc.y, acc11);
            acc20 = fmaf(xr.z, xc.x, acc20); acc21 = fmaf(xr.z, xc.y, acc21);
            acc30 = fmaf(xr.w, xc.x, acc30); acc31 = fmaf(xr.w, xc.y, acc31);
        }
        DT[(rg*4+0)*33 + cg*2] = acc00; DT[(rg*4+0)*33 + cg*2+1] = acc01;
        DT[(rg*4+1)*33 + cg*2] = acc10; DT[(rg*4+1)*33 + cg*2+1] = acc11;
        DT[(rg*4+2)*33 + cg*2] = acc20; DT[(rg*4+2)*33 + cg*2+1] = acc21;
        DT[(rg*4+3)*33 + cg*2] = acc30; DT[(rg*4+3)*33 + cg*2+1] = acc31;
        __syncthreads();
        if (ownRow >= 0) {
            // rank by x2[j] - 2*dot  (x2[i] is a per-row constant, drops out)
            for (int c = 0; c < 32; ++c) {
                float cand = fmaf(-2.f, DT[ownRow*33 + c], X2C[c]);
                top.insert(cand, c0 + c);
            }
        }
    }
    if (ownRow >= 0) {
        int grow = batch*NN + r0 + ownRow;
#pragma unroll
        for (int s = 0; s < 16; ++s) idxout[grow*16 + s] = top.id[s];   // set order irrelevant
    }
}

// ---------------- final: out0=tgt+att; LN0; @Wl^T+bl; z=tgt+; LN1; transpose write ----------------
__global__ __launch_bounds__(256) void final_kernel(
    const float* __restrict__ tgt, const float* __restrict__ att,
    const float* __restrict__ Wl, const float* __restrict__ bl,
    const float* __restrict__ g0, const float* __restrict__ b0,
    const float* __restrict__ g1, const float* __restrict__ b1,
    float* __restrict__ outp)
{
    __shared__ float WL[128*128];
    int tid = threadIdx.x;
    for (int f = tid; f < 16384; f += 256) {
        int c = f >> 7, d = f & 127;
        WL[d*128 + (c ^ (d & 14))] = Wl[f];
    }
    __syncthreads();
    int lane = tid & 63, wave = tid >> 6;
    float2 gg0 = *(const float2*)&g0[2*lane];
    float2 bb0 = *(const float2*)&b0[2*lane];
    float2 gg1 = *(const float2*)&g1[2*lane];
    float2 bb1 = *(const float2*)&b1[2*lane];
    float2 bl2 = *(const float2*)&bl[2*lane];
    for (int it = 0; it < 4; ++it) {                     // grid 256 x 64 rows
        int row0 = blockIdx.x*64 + it*16 + wave*4;
        float2 tg[4];
        float lnx[4], lny[4];
#pragma unroll
        for (int r = 0; r < 4; ++r) {
            int row = row0 + r;
            tg[r] = *(const float2*)&tgt[row*128 + 2*lane];
            float2 at = *(const float2*)&att[row*128 + 2*lane];
            float ox = tg[r].x + at.x, oy = tg[r].y + at.y;
            float s = ox + oy;
#pragma unroll
            for (int off = 1; off < 64; off <<= 1) s += __shfl_xor(s, off, 64);
            float mu = s * (1.f/128.f);
            float dx = ox - mu, dy = oy - mu;
            float vv = fmaf(dx, dx, dy*dy);
#pragma unroll
            for (int off = 1; off < 64; off <<= 1) vv += __shfl_xor(vv, off, 64);
            float rstd = rsqrtf(vv * (1.f/128.f) + 1e-5f);
            lnx[r] = dx * rstd * gg0.x + bb0.x;          // dim 2*lane
            lny[r] = dy * rstd * gg0.y + bb0.y;          // dim 2*lane+1
        }
        float2 acc[4];
#pragma unroll
        for (int r = 0; r < 4; ++r) { acc[r].x = 0.f; acc[r].y = 0.f; }
#pragma unroll 8
        for (int dh = 0; dh < 64; ++dh) {
            int cidx = (2*lane) ^ ((2*dh) & 14);         // (2dh+1)&14 == (2dh)&14
            float2 wa = *(const float2*)&WL[(2*dh)*128 + cidx];
            float2 wb = *(const float2*)&WL[(2*dh+1)*128 + cidx];
#pragma unroll
            for (int r = 0; r < 4; ++r) {
                float xa = rl_f(lnx[r], dh);             // dim 2*dh
                float xb = rl_f(lny[r], dh);             // dim 2*dh+1
                acc[r].x = fmaf(xa, wa.x, acc[r].x);
                acc[r].y = fmaf(xa, wa.y, acc[r].y);
                acc[r].x = fmaf(xb, wb.x, acc[r].x);
                acc[r].y = fmaf(xb, wb.y, acc[r].y);
            }
        }
#pragma unroll
        for (int r = 0; r < 4; ++r) {
            int row = row0 + r;
            float zx = tg[r].x + acc[r].x + bl2.x;
            float zy = tg[r].y + acc[r].y + bl2.y;
            float s = zx + zy;
#pragma unroll
            for (int off = 1; off < 64; off <<= 1) s += __shfl_xor(s, off, 64);
            float mu = s * (1.f/128.f);
            float dx = zx - mu, dy = zy - mu;
            float vv = fmaf(dx, dx, dy*dy);
#pragma unroll
            for (int off = 1; off < 64; off <<= 1) vv += __shfl_xor(vv, off, 64);
            float rstd = rsqrtf(vv * (1.f/128.f) + 1e-5f);
            float2 res;
            res.x = dx * rstd * gg1.x + bb1.x;
            res.y = dy * rstd * gg1.y + bb1.y;
            int b = row >> 12, n = row & 4095;
            *(float2*)&outp[((size_t)n*NB + b)*128 + 2*lane] = res;   // [N,B,C]
        }
    }
}

extern "C" void kernel_launch(void* const* d_in, const int* in_sizes, int n_in,
                              void* d_out, int out_size, void* d_ws, size_t ws_size,
                              hipStream_t stream)
{
    (void)in_sizes; (void)n_in; (void)out_size; (void)ws_size;
    const float* src = (const float*)d_in[0];
    const float* tgt = (const float*)d_in[1];
    const float* Wq0 = (const float*)d_in[2];
    const float* Wk0 = (const float*)d_in[3];
    const float* Wv0 = (const float*)d_in[4];
    const float* Wq1 = (const float*)d_in[5];
    const float* Wk1 = (const float*)d_in[6];
    const float* Wv1 = (const float*)d_in[7];
    const float* Wp0 = (const float*)d_in[8];
    const float* bp0 = (const float*)d_in[9];
    const float* Wp1 = (const float*)d_in[10];
    const float* bp1 = (const float*)d_in[11];
    const float* Wl  = (const float*)d_in[12];
    const float* bl  = (const float*)d_in[13];
    const float* g0  = (const float*)d_in[14];
    const float* b0  = (const float*)d_in[15];
    const float* g1  = (const float*)d_in[16];
    const float* b1  = (const float*)d_in[17];
    float* out = (float*)d_out;

    // workspace layout (~50.3 MB)
    float* A0   = (float*)d_ws;
    float* A1   = A0 + 2097152;
    float* A2   = A1 + 2097152;
    float* A3   = A2 + 2097152;
    float* A4   = A3 + 2097152;
    float* OUT1 = A4 + 2097152;               // also reused as ATT2 output
    int*   IDX1 = (int*)(OUT1 + 2097152);
    int*   IDX2 = IDX1 + NROWS*16;
    float* X2G  = (float*)(IDX2 + NROWS*16);
    float* WKP0 = X2G + NROWS;
    float* BK0  = WKP0 + 384;
    float* WVP0 = BK0 + 128;
    float* BV0  = WVP0 + 384;
    float* MK1  = BV0 + 128;
    float* BK1  = MK1 + 16384;
    float* MV1  = BK1 + 128;
    float* BV1  = MV1 + 16384;

    combo_small<<<dim3(2), dim3(512), 0, stream>>>(Wk0, Wv0, Wp0, bp0, WKP0, BK0, WVP0, BV0);
    combo_big<<<dim3(129), dim3(256), 0, stream>>>(Wk1, Wv1, Wp1, bp1, MK1, BK1, MV1, BV1);
    srcproj<<<dim3(8192), dim3(256), 0, stream>>>(src, WKP0, WVP0, A3, A4);
    knn1_kernel<<<dim3(4096), dim3(256), 0, stream>>>(src, IDX1);
    matmul128<<<dim3(512), dim3(256), 0, stream>>>(tgt, Wq0, A0);   // tgtQ
    matmul128<<<dim3(512), dim3(256), 0, stream>>>(tgt, Wk0, A1);   // tgtK
    matmul128<<<dim3(512), dim3(256), 0, stream>>>(tgt, Wv0, A2);   // tgtV
    attn_kernel<<<dim3(4096), dim3(256), 0, stream>>>(A0, A3, A1, A4, A2, BK0, BV0, IDX1, OUT1, X2G);
    knn2_kernel<<<dim3(256), dim3(256), 0, stream>>>(OUT1, X2G, IDX2);
    matmul128<<<dim3(512), dim3(256), 0, stream>>>(OUT1, Wq1, A0);  // Q1
    matmul128<<<dim3(512), dim3(256), 0, stream>>>(OUT1, Wk1, A1);  // outK
    matmul128<<<dim3(512), dim3(256), 0, stream>>>(OUT1, Wv1, A2);  // outV
    matmul128<<<dim3(512), dim3(256), 0, stream>>>(OUT1, MK1, A3);  // outMk
    matmul128<<<dim3(512), dim3(256), 0, stream>>>(OUT1, MV1, A4);  // outMv
    attn_kernel<<<dim3(4096), dim3(256), 0, stream>>>(A0, A3, A1, A4, A2, BK1, BV1, IDX2, OUT1, nullptr);
    final_kernel<<<dim3(256), dim3(256), 0, stream>>>(tgt, OUT1, Wl, bl, g0, b0, g1, b1, out);
}

// Round 2
// 843.199 us; speedup vs baseline: 2.6055x; 2.6055x over previous
//
#include <hip/hip_runtime.h>
#include <math.h>

#define NB 4
#define NN 4096
#define NC 128
#define NROWS (NB*NN)
#define SCALE_F 0.08838834764831845f   // 1/sqrt(128)

__device__ __forceinline__ float rl_f(float x, int l) {
    return __int_as_float(__builtin_amdgcn_readlane(__float_as_int(x), l));
}

// ---- 16-deep sorted (ascending) register lists, all named scalars ----
#define DECL16V \
    float v0=INFINITY,v1=INFINITY,v2=INFINITY,v3=INFINITY,v4=INFINITY,v5=INFINITY,v6=INFINITY,v7=INFINITY, \
          v8=INFINITY,v9=INFINITY,v10=INFINITY,v11=INFINITY,v12=INFINITY,v13=INFINITY,v14=INFINITY,v15=INFINITY;

#define DECL16I \
    int i0=0x7fffffff,i1=0x7fffffff,i2=0x7fffffff,i3=0x7fffffff,i4=0x7fffffff,i5=0x7fffffff,i6=0x7fffffff,i7=0x7fffffff, \
        i8=0x7fffffff,i9=0x7fffffff,i10=0x7fffffff,i11=0x7fffffff,i12=0x7fffffff,i13=0x7fffffff,i14=0x7fffffff,i15=0x7fffffff;

// branchless sorted insert of value d_ (strict <, equal values keep earlier entry first)
#define INSERT16V(dv) do { float d_=(dv); \
    bool m0=d_<v0,m1=d_<v1,m2=d_<v2,m3=d_<v3,m4=d_<v4,m5=d_<v5,m6=d_<v6,m7=d_<v7, \
         m8=d_<v8,m9=d_<v9,m10=d_<v10,m11=d_<v11,m12=d_<v12,m13=d_<v13,m14=d_<v14,m15=d_<v15; \
    v15=m14?v14:(m15?d_:v15); v14=m13?v13:(m14?d_:v14); v13=m12?v12:(m13?d_:v13); v12=m11?v11:(m12?d_:v12); \
    v11=m10?v10:(m11?d_:v11); v10=m9?v9:(m10?d_:v10); v9 =m8?v8:(m9?d_:v9);  v8 =m7?v7:(m8?d_:v8); \
    v7 =m6?v6:(m7?d_:v7);   v6 =m5?v5:(m6?d_:v6);   v5 =m4?v4:(m5?d_:v5);  v4 =m3?v3:(m4?d_:v4); \
    v3 =m2?v2:(m3?d_:v3);   v2 =m1?v1:(m2?d_:v2);   v1 =m0?v0:(m1?d_:v1);  v0 =m0?d_:v0; } while(0)

#define INSERT16VI(dv,jv) do { float d_=(dv); int j_=(jv); \
    bool m0=d_<v0,m1=d_<v1,m2=d_<v2,m3=d_<v3,m4=d_<v4,m5=d_<v5,m6=d_<v6,m7=d_<v7, \
         m8=d_<v8,m9=d_<v9,m10=d_<v10,m11=d_<v11,m12=d_<v12,m13=d_<v13,m14=d_<v14,m15=d_<v15; \
    v15=m14?v14:(m15?d_:v15); i15=m14?i14:(m15?j_:i15); \
    v14=m13?v13:(m14?d_:v14); i14=m13?i13:(m14?j_:i14); \
    v13=m12?v12:(m13?d_:v13); i13=m12?i12:(m13?j_:i13); \
    v12=m11?v11:(m12?d_:v12); i12=m11?i11:(m12?j_:i12); \
    v11=m10?v10:(m11?d_:v11); i11=m10?i10:(m11?j_:i11); \
    v10=m9?v9:(m10?d_:v10);   i10=m9?i9:(m10?j_:i10); \
    v9 =m8?v8:(m9?d_:v9);     i9 =m8?i8:(m9?j_:i9); \
    v8 =m7?v7:(m8?d_:v8);     i8 =m7?i7:(m8?j_:i8); \
    v7 =m6?v6:(m7?d_:v7);     i7 =m6?i6:(m7?j_:i7); \
    v6 =m5?v5:(m6?d_:v6);     i6 =m5?i5:(m6?j_:i6); \
    v5 =m4?v4:(m5?d_:v5);     i5 =m4?i4:(m5?j_:i5); \
    v4 =m3?v3:(m4?d_:v4);     i4 =m3?i3:(m4?j_:i4); \
    v3 =m2?v2:(m3?d_:v3);     i3 =m2?i2:(m3?j_:i3); \
    v2 =m1?v1:(m2?d_:v2);     i2 =m1?i1:(m2?j_:i2); \
    v1 =m0?v0:(m1?d_:v1);     i1 =m0?i0:(m1?j_:i1); \
    v0 =m0?d_:v0;             i0 =m0?j_:i0; } while(0)

// pop head under per-lane predicate p (shift list down, refill worst with +inf)
#define POP16V(p) do { bool p_=(p); \
    v0=p_?v1:v0; v1=p_?v2:v1; v2=p_?v3:v2; v3=p_?v4:v3; v4=p_?v5:v4; v5=p_?v6:v5; v6=p_?v7:v6; v7=p_?v8:v7; \
    v8=p_?v9:v8; v9=p_?v10:v9; v10=p_?v11:v10; v11=p_?v12:v11; v12=p_?v13:v12; v13=p_?v14:v13; v14=p_?v15:v14; \
    v15=p_?INFINITY:v15; } while(0)

#define POP16VI(p) do { bool p_=(p); \
    v0=p_?v1:v0; i0=p_?i1:i0; v1=p_?v2:v1; i1=p_?i2:i1; v2=p_?v3:v2; i2=p_?i3:i2; v3=p_?v4:v3; i3=p_?i4:i3; \
    v4=p_?v5:v4; i4=p_?i5:i4; v5=p_?v6:v5; i5=p_?i6:i5; v6=p_?v7:v6; i6=p_?i7:i6; v7=p_?v8:v7; i7=p_?i8:i7; \
    v8=p_?v9:v8; i8=p_?i9:i8; v9=p_?v10:v9; i9=p_?i10:i9; v10=p_?v11:v10; i10=p_?i11:i10; \
    v11=p_?v12:v11; i11=p_?i12:i11; v12=p_?v13:v12; i12=p_?i13:i12; v13=p_?v14:v13; i13=p_?i14:i13; \
    v14=p_?v15:v14; i14=p_?i15:i14; v15=p_?INFINITY:v15; i15=p_?0x7fffffff:i15; } while(0)

// ---------------- tiny weight combos ----------------
__global__ void combo_small(const float* __restrict__ Wk0, const float* __restrict__ Wv0,
                            const float* __restrict__ Wp0, const float* __restrict__ bp0,
                            float* __restrict__ WKP0, float* __restrict__ BK0,
                            float* __restrict__ WVP0, float* __restrict__ BV0)
{
    int task = blockIdx.x * 512 + threadIdx.x;
    if (task >= 1024) return;
    int mat = task >> 9; int rem = task & 511;
    int c = rem >> 2, t = rem & 3;
    const float* W = mat ? Wv0 : Wk0;
    float s = 0.f;
    if (t < 3) {
        for (int d = 0; d < 128; ++d) s = fmaf(W[c*128+d], Wp0[d*3+t], s);
        (mat ? WVP0 : WKP0)[c*3+t] = s;
    } else {
        for (int d = 0; d < 128; ++d) s = fmaf(W[c*128+d], bp0[d], s);
        (mat ? BV0 : BK0)[c] = s;
    }
}

__global__ void combo_big(const float* __restrict__ Wk1, const float* __restrict__ Wv1,
                          const float* __restrict__ Wp1, const float* __restrict__ bp1,
                          float* __restrict__ MK1, float* __restrict__ BK1,
                          float* __restrict__ MV1, float* __restrict__ BV1)
{
    int task = blockIdx.x * 256 + threadIdx.x;
    if (task >= 33024) return;
    int mat = task >= 16512; int rem = mat ? task - 16512 : task;
    const float* W = mat ? Wv1 : Wk1;
    if (rem < 16384) {
        int c = rem >> 7, t = rem & 127;
        float s = 0.f;
        for (int d = 0; d < 128; ++d) s = fmaf(W[c*128+d], Wp1[d*128+t], s);
        (mat ? MV1 : MK1)[rem] = s;
    } else {
        int c = rem - 16384;
        float s = 0.f;
        for (int d = 0; d < 128; ++d) s = fmaf(W[c*128+d], bp1[d], s);
        (mat ? BV1 : BK1)[c] = s;
    }
}

__global__ void srcproj(const float* __restrict__ src, const float* __restrict__ WKP0,
                        const float* __restrict__ WVP0,
                        float* __restrict__ srcKp, float* __restrict__ srcVp)
{
    int gid = blockIdx.x * 256 + threadIdx.x;
    int i = gid >> 7, c = gid & 127;
    float s0 = src[i*3+0], s1 = src[i*3+1], s2 = src[i*3+2];
    srcKp[gid] = fmaf(s0, WKP0[c*3+0], fmaf(s1, WKP0[c*3+1], s2*WKP0[c*3+2]));
    srcVp[gid] = fmaf(s0, WVP0[c*3+0], fmaf(s1, WVP0[c*3+1], s2*WVP0[c*3+2]));
}

// ---------------- KNN stage 1 (3-D), one wave per row, value-threshold 2-pass ----------------
__global__ __launch_bounds__(256) void knn1_kernel(const float* __restrict__ src,
                                                   int* __restrict__ idxout)
{
    int lane = threadIdx.x & 63, wave = threadIdx.x >> 6;
    int b7 = blockIdx.x & 7, sub = blockIdx.x >> 3;      // grid 4096
    int batch = b7 >> 1;
    int rib = (sub*2 + (b7 & 1))*4 + wave;
    int row = batch*NN + rib;
    const float* sb = src + batch*NN*3;
    float xi0 = sb[rib*3], xi1 = sb[rib*3+1], xi2 = sb[rib*3+2];

    // pass 1: per-lane sorted 16 smallest VALUES over 64 candidates each
    DECL16V
    for (int it = 0; it < 64; ++it) {
        int j = it*64 + lane;
        float dx = xi0 - sb[j*3], dy = xi1 - sb[j*3+1], dz = xi2 - sb[j*3+2];
        float d2 = fmaf(dx, dx, fmaf(dy, dy, dz*dz));
        if (__ballot(d2 < v15)) INSERT16V(d2);
    }
    // wave pop-merge: extract 16 smallest of the union (with multiplicity) -> T
    float T = INFINITY;
    for (int t = 0; t < 16; ++t) {
        float g = v0;
#pragma unroll
        for (int off = 1; off < 64; off <<= 1) g = fminf(g, __shfl_xor(g, off, 64));
        unsigned long long b = __ballot(v0 == g);
        int f = __ffsll((long long)b) - 1;
        POP16V(lane == f);
        T = g;
    }
    // pass 2a: emit all strictly-less (positions 0..c_lt-1, order irrelevant: set-equal)
    unsigned long long below_mask = (lane == 63) ? 0x7fffffffffffffffull : ((1ull << lane) - 1ull);
    int base = 0;
    for (int it = 0; it < 64; ++it) {
        int j = it*64 + lane;
        float dx = xi0 - sb[j*3], dy = xi1 - sb[j*3+1], dz = xi2 - sb[j*3+2];
        float d2 = fmaf(dx, dx, fmaf(dy, dy, dz*dz));
        unsigned long long blt = __ballot(d2 < T);
        if (d2 < T) idxout[row*16 + base + __popcll(blt & below_mask)] = j;
        base += __popcll(blt);
    }
    // pass 2b: fill remaining slots with ties (== T) by smallest index
    for (int it = 0; it < 64 && base < 16; ++it) {
        int j = it*64 + lane;
        float dx = xi0 - sb[j*3], dy = xi1 - sb[j*3+1], dz = xi2 - sb[j*3+2];
        float d2 = fmaf(dx, dx, fmaf(dy, dy, dz*dz));
        unsigned long long beq = __ballot(d2 == T);
        int bel = __popcll(beq & below_mask);
        if (d2 == T && base + bel < 16) idxout[row*16 + base + bel] = j;
        base += __popcll(beq);
    }
}

// ---------------- generic [M,128]@[128,128]^T matmul (Y = X @ W^T) ----------------
__global__ __launch_bounds__(256) void matmul128(const float* __restrict__ X,
                                                 const float* __restrict__ W,
                                                 float* __restrict__ Y)
{
    __shared__ float WL[128*128];
    int tid = threadIdx.x;
    for (int f = tid; f < 16384; f += 256) {
        int c = f >> 7, d = f & 127;
        WL[d*128 + (c ^ (d & 14))] = W[f];
    }
    __syncthreads();
    int lane = tid & 63, wave = tid >> 6;
#pragma unroll
    for (int it = 0; it < 2; ++it) {
        int row0 = blockIdx.x*32 + it*16 + wave*4;
        float x0[4], x1[4];
#pragma unroll
        for (int r = 0; r < 4; ++r) {
            x0[r] = X[(row0+r)*128 + lane];
            x1[r] = X[(row0+r)*128 + lane + 64];
        }
        float2 acc[4];
#pragma unroll
        for (int r = 0; r < 4; ++r) { acc[r].x = 0.f; acc[r].y = 0.f; }
#pragma unroll 8
        for (int d = 0; d < 64; ++d) {
            int cidx = (2*lane) ^ (d & 14);
            float2 wa = *(const float2*)&WL[d*128 + cidx];
            float2 wb = *(const float2*)&WL[(d+64)*128 + cidx];
#pragma unroll
            for (int r = 0; r < 4; ++r) {
                float xa = rl_f(x0[r], d);
                float xb = rl_f(x1[r], d);
                acc[r].x = fmaf(xa, wa.x, acc[r].x);
                acc[r].y = fmaf(xa, wa.y, acc[r].y);
                acc[r].x = fmaf(xb, wb.x, acc[r].x);
                acc[r].y = fmaf(xb, wb.y, acc[r].y);
            }
        }
#pragma unroll
        for (int r = 0; r < 4; ++r) {
            *(float2*)&Y[(row0+r)*128 + 2*lane] = acc[r];
        }
    }
}

// ---------------- gather attention ----------------
__global__ __launch_bounds__(256) void attn_kernel(
    const float* __restrict__ Q,  const float* __restrict__ RK, const float* __restrict__ GK,
    const float* __restrict__ RV, const float* __restrict__ GV,
    const float* __restrict__ bk, const float* __restrict__ bv,
    const int* __restrict__ idx, float* __restrict__ outp, float* __restrict__ x2out)
{
    int lane = threadIdx.x & 63, wave = threadIdx.x >> 6;
    int b7 = blockIdx.x & 7, sub = blockIdx.x >> 3;
    int batch = b7 >> 1;
    int rib = (sub*2 + (b7 & 1))*4 + wave;
    int row = batch*NN + rib;
    const float* RKb = RK + (size_t)batch*NN*NC;
    const float* GKb = GK + (size_t)batch*NN*NC;
    const float* RVb = RV + (size_t)batch*NN*NC;
    const float* GVb = GV + (size_t)batch*NN*NC;

    float q0 = Q[row*NC + lane], q1 = Q[row*NC + lane + 64];
    float rki0 = RKb[rib*NC + lane], rki1 = RKb[rib*NC + lane + 64];
    float rvi0 = RVb[rib*NC + lane], rvi1 = RVb[rib*NC + lane + 64];
    float bka = bk[lane], bkb = bk[lane+64];
    float bva = bv[lane], bvb = bv[lane+64];

    int jarr[16];
#pragma unroll
    for (int k = 0; k < 16; ++k) jarr[k] = idx[row*16 + k];

    float sc[16];
#pragma unroll
    for (int k = 0; k < 16; ++k) {
        int j = jarr[k];
        float kk0 = rki0 - RKb[j*NC + lane]      + GKb[j*NC + lane]      + bka;
        float kk1 = rki1 - RKb[j*NC + lane + 64] + GKb[j*NC + lane + 64] + bkb;
        float p = fmaf(q0, kk0, q1*kk1);
#pragma unroll
        for (int off = 1; off < 64; off <<= 1) p += __shfl_xor(p, off, 64);
        sc[k] = p * SCALE_F;
    }
    float m = sc[0];
#pragma unroll
    for (int k = 1; k < 16; ++k) m = fmaxf(m, sc[k]);
    float wsum = 0.f, w[16];
#pragma unroll
    for (int k = 0; k < 16; ++k) { w[k] = expf(sc[k] - m); wsum += w[k]; }
    float inv = 1.f / wsum;
    float a0 = 0.f, a1 = 0.f;
#pragma unroll
    for (int k = 0; k < 16; ++k) {
        int j = jarr[k];
        float a = w[k] * inv;
        float vv0 = rvi0 - RVb[j*NC + lane]      + GVb[j*NC + lane]      + bva;
        float vv1 = rvi1 - RVb[j*NC + lane + 64] + GVb[j*NC + lane + 64] + bvb;
        a0 = fmaf(a, vv0, a0);
        a1 = fmaf(a, vv1, a1);
    }
    outp[row*NC + lane]      = a0;
    outp[row*NC + lane + 64] = a1;
    if (x2out != nullptr) {
        float x2 = fmaf(a0, a0, a1*a1);
#pragma unroll
        for (int off = 1; off < 64; off <<= 1) x2 += __shfl_xor(x2, off, 64);
        if (lane == 0) x2out[row] = x2;
    }
}

// ---------------- KNN stage 2 (128-D), fused Gram + parallel register top-16 ----------------
// block: 64 rows x full 4096-col sweep in 128-col tiles. 512 threads (8 waves).
// LDS exactly 128 KiB. Rotation swizzle (d+4c)&127 keeps b128 reads conflict-free.
__global__ __launch_bounds__(512) void knn2_kernel(const float* __restrict__ X,
                                                   const float* __restrict__ x2g,
                                                   int* __restrict__ idxout)
{
    __shared__ float XR[64*128];    // 32 KB  rows, [r][d] plain (broadcast reads)
    __shared__ float XC[128*128];   // 64 KB  cols, [c][(d+4c)&127]
    __shared__ float DT[64*128];    // 32 KB  dots, [r][(col+4r)&127]
    int tid = threadIdx.x;
    int xcd = blockIdx.x & 7, sub = blockIdx.x >> 3;     // grid 256; XCD pair owns one batch
    int batch = xcd >> 1;
    int rowblk = sub*2 + (xcd & 1);                      // 0..63
    const float* Xb  = X   + (size_t)batch*NN*NC;
    const float* x2b = x2g + (size_t)batch*NN;
    int r0 = rowblk*64;

    // stage row band [64][128]
    for (int f = tid; f < 64*32; f += 512) {
        int r = f >> 5, d4 = f & 31;
        *(float4*)&XR[r*128 + d4*4] = *(const float4*)&Xb[(r0 + r)*NC + d4*4];
    }

    // compute mapping: rg=tid>>5 (16), cg=tid&31; rows rg*4+i, cols cg+32k
    int rg = tid >> 5, cg = tid & 31;
    // scan mapping: srow=tid>>3 (64), slot=tid&7; cols slot+8k (k=0..15)
    int srow = tid >> 3, slot = tid & 7;

    DECL16V
    DECL16I

    for (int t = 0; t < 32; ++t) {
        int c0 = t*128;
        __syncthreads();   // prev compute's XC reads + prev scan's DT reads done
        // stage col tile [128][128] with rotation swizzle
        for (int f = tid; f < 128*32; f += 512) {
            int c = f >> 5, d4 = f & 31;
            float4 g = *(const float4*)&Xb[(c0 + c)*NC + d4*4];
            *(float4*)&XC[c*128 + ((d4*4 + 4*c) & 127)] = g;
        }
        // scan previous tile's dots (t-1)
        if (t > 0) {
            int cp = (t-1)*128;
#pragma unroll
            for (int k = 0; k < 16; ++k) {
                int col = slot + 8*k;
                float dot = DT[srow*128 + ((col + 4*srow) & 127)];
                float d2 = fmaf(-2.f, dot, x2b[cp + col]);
                if (__ballot(d2 < v15)) INSERT16VI(d2, cp + col);
            }
        }
        __syncthreads();   // XC staged, DT free to overwrite
        // compute 64x128 dot tile, micro 4 rows x 4 cols
        float acc[4][4];
#pragma unroll
        for (int i = 0; i < 4; ++i)
#pragma unroll
            for (int k = 0; k < 4; ++k) acc[i][k] = 0.f;
        for (int dc = 0; dc < 128; dc += 4) {
            float4 xr[4], xc[4];
#pragma unroll
            for (int i = 0; i < 4; ++i) xr[i] = *(const float4*)&XR[(rg*4+i)*128 + dc];
#pragma unroll
            for (int k = 0; k < 4; ++k) {
                int c = cg + 32*k;
                xc[k] = *(const float4*)&XC[c*128 + ((dc + 4*c) & 127)];
            }
#pragma unroll
            for (int i = 0; i < 4; ++i)
#pragma unroll
                for (int k = 0; k < 4; ++k) {
                    acc[i][k] = fmaf(xr[i].x, xc[k].x, acc[i][k]);
                    acc[i][k] = fmaf(xr[i].y, xc[k].y, acc[i][k]);
                    acc[i][k] = fmaf(xr[i].z, xc[k].z, acc[i][k]);
                    acc[i][k] = fmaf(xr[i].w, xc[k].w, acc[i][k]);
                }
        }
#pragma unroll
        for (int i = 0; i < 4; ++i) {
            int r = rg*4 + i;
#pragma unroll
            for (int k = 0; k < 4; ++k) {
                int col = cg + 32*k;
                DT[r*128 + ((col + 4*r) & 127)] = acc[i][k];
            }
        }
    }
    __syncthreads();
    // scan last tile
    {
        int cp = 31*128;
#pragma unroll
        for (int k = 0; k < 16; ++k) {
            int col = slot + 8*k;
            float dot = DT[srow*128 + ((col + 4*srow) & 127)];
            float d2 = fmaf(-2.f, dot, x2b[cp + col]);
            if (__ballot(d2 < v15)) INSERT16VI(d2, cp + col);
        }
    }
    // merge the 8 per-thread lists of each row (8-lane groups), lexicographic pop-merge
    int grow = batch*NN + r0 + srow;
    for (int t = 0; t < 16; ++t) {
        float gv = v0; int gi = i0;
#pragma unroll
        for (int off = 1; off < 8; off <<= 1) {
            float ov = __shfl_xor(gv, off, 64);
            int   oi = __shfl_xor(gi, off, 64);
            bool take = (ov < gv) || (ov == gv && oi < gi);
            gv = take ? ov : gv; gi = take ? oi : gi;
        }
        bool win = (v0 == gv) && (i0 == gi);
        if (win) idxout[grow*16 + t] = gi;
        POP16VI(win);
    }
}

// ---------------- final fused LN / linear / LN / transpose ----------------
__global__ __launch_bounds__(256) void final_kernel(
    const float* __restrict__ tgt, const float* __restrict__ att,
    const float* __restrict__ Wl, const float* __restrict__ bl,
    const float* __restrict__ g0, const float* __restrict__ b0,
    const float* __restrict__ g1, const float* __restrict__ b1,
    float* __restrict__ outp)
{
    __shared__ float WL[128*128];
    int tid = threadIdx.x;
    for (int f = tid; f < 16384; f += 256) {
        int c = f >> 7, d = f & 127;
        WL[d*128 + (c ^ (d & 14))] = Wl[f];
    }
    __syncthreads();
    int lane = tid & 63, wave = tid >> 6;
    float2 gg0 = *(const float2*)&g0[2*lane];
    float2 bb0 = *(const float2*)&b0[2*lane];
    float2 gg1 = *(const float2*)&g1[2*lane];
    float2 bb1 = *(const float2*)&b1[2*lane];
    float2 bl2 = *(const float2*)&bl[2*lane];
    for (int it = 0; it < 4; ++it) {
        int row0 = blockIdx.x*64 + it*16 + wave*4;
        float2 tg[4];
        float lnx[4], lny[4];
#pragma unroll
        for (int r = 0; r < 4; ++r) {
            int row = row0 + r;
            tg[r] = *(const float2*)&tgt[row*128 + 2*lane];
            float2 at = *(const float2*)&att[row*128 + 2*lane];
            float ox = tg[r].x + at.x, oy = tg[r].y + at.y;
            float s = ox + oy;
#pragma unroll
            for (int off = 1; off < 64; off <<= 1) s += __shfl_xor(s, off, 64);
            float mu = s * (1.f/128.f);
            float dx = ox - mu, dy = oy - mu;
            float vv = fmaf(dx, dx, dy*dy);
#pragma unroll
            for (int off = 1; off < 64; off <<= 1) vv += __shfl_xor(vv, off, 64);
            float rstd = rsqrtf(vv * (1.f/128.f) + 1e-5f);
            lnx[r] = dx * rstd * gg0.x + bb0.x;
            lny[r] = dy * rstd * gg0.y + bb0.y;
        }
        float2 acc[4];
#pragma unroll
        for (int r = 0; r < 4; ++r) { acc[r].x = 0.f; acc[r].y = 0.f; }
#pragma unroll 8
        for (int dh = 0; dh < 64; ++dh) {
            int cidx = (2*lane) ^ ((2*dh) & 14);
            float2 wa = *(const float2*)&WL[(2*dh)*128 + cidx];
            float2 wb = *(const float2*)&WL[(2*dh+1)*128 + cidx];
#pragma unroll
            for (int r = 0; r < 4; ++r) {
                float xa = rl_f(lnx[r], dh);
                float xb = rl_f(lny[r], dh);
                acc[r].x = fmaf(xa, wa.x, acc[r].x);
                acc[r].y = fmaf(xa, wa.y, acc[r].y);
                acc[r].x = fmaf(xb, wb.x, acc[r].x);
                acc[r].y = fmaf(xb, wb.y, acc[r].y);
            }
        }
#pragma unroll
        for (int r = 0; r < 4; ++r) {
            int row = row0 + r;
            float zx = tg[r].x + acc[r].x + bl2.x;
            float zy = tg[r].y + acc[r].y + bl2.y;
            float s = zx + zy;
#pragma unroll
            for (int off = 1; off < 64; off <<= 1) s += __shfl_xor(s, off, 64);
            float mu = s * (1.f/128.f);
            float dx = zx - mu, dy = zy - mu;
            float vv = fmaf(dx, dx, dy*dy);
#pragma unroll
            for (int off = 1; off < 64; off <<= 1) vv += __shfl_xor(vv, off, 64);
            float rstd = rsqrtf(vv * (1.f/128.f) + 1e-5f);
            float2 res;
            res.x = dx * rstd * gg1.x + bb1.x;
            res.y = dy * rstd * gg1.y + bb1.y;
            int b = row >> 12, n = row & 4095;
            *(float2*)&outp[((size_t)n*NB + b)*128 + 2*lane] = res;
        }
    }
}

extern "C" void kernel_launch(void* const* d_in, const int* in_sizes, int n_in,
                              void* d_out, int out_size, void* d_ws, size_t ws_size,
                              hipStream_t stream)
{
    (void)in_sizes; (void)n_in; (void)out_size; (void)ws_size;
    const float* src = (const float*)d_in[0];
    const float* tgt = (const float*)d_in[1];
    const float* Wq0 = (const float*)d_in[2];
    const float* Wk0 = (const float*)d_in[3];
    const float* Wv0 = (const float*)d_in[4];
    const float* Wq1 = (const float*)d_in[5];
    const float* Wk1 = (const float*)d_in[6];
    const float* Wv1 = (const float*)d_in[7];
    const float* Wp0 = (const float*)d_in[8];
    const float* bp0 = (const float*)d_in[9];
    const float* Wp1 = (const float*)d_in[10];
    const float* bp1 = (const float*)d_in[11];
    const float* Wl  = (const float*)d_in[12];
    const float* bl  = (const float*)d_in[13];
    const float* g0  = (const float*)d_in[14];
    const float* b0  = (const float*)d_in[15];
    const float* g1  = (const float*)d_in[16];
    const float* b1  = (const float*)d_in[17];
    float* out = (float*)d_out;

    float* A0   = (float*)d_ws;
    float* A1   = A0 + 2097152;
    float* A2   = A1 + 2097152;
    float* A3   = A2 + 2097152;
    float* A4   = A3 + 2097152;
    float* OUT1 = A4 + 2097152;
    int*   IDX1 = (int*)(OUT1 + 2097152);
    int*   IDX2 = IDX1 + NROWS*16;
    float* X2G  = (float*)(IDX2 + NROWS*16);
    float* WKP0 = X2G + NROWS;
    float* BK0  = WKP0 + 384;
    float* WVP0 = BK0 + 128;
    float* BV0  = WVP0 + 384;
    float* MK1  = BV0 + 128;
    float* BK1  = MK1 + 16384;
    float* MV1  = BK1 + 128;
    float* BV1  = MV1 + 16384;

    combo_small<<<dim3(2), dim3(512), 0, stream>>>(Wk0, Wv0, Wp0, bp0, WKP0, BK0, WVP0, BV0);
    combo_big<<<dim3(129), dim3(256), 0, stream>>>(Wk1, Wv1, Wp1, bp1, MK1, BK1, MV1, BV1);
    srcproj<<<dim3(8192), dim3(256), 0, stream>>>(src, WKP0, WVP0, A3, A4);
    knn1_kernel<<<dim3(4096), dim3(256), 0, stream>>>(src, IDX1);
    matmul128<<<dim3(512), dim3(256), 0, stream>>>(tgt, Wq0, A0);
    matmul128<<<dim3(512), dim3(256), 0, stream>>>(tgt, Wk0, A1);
    matmul128<<<dim3(512), dim3(256), 0, stream>>>(tgt, Wv0, A2);
    attn_kernel<<<dim3(4096), dim3(256), 0, stream>>>(A0, A3, A1, A4, A2, BK0, BV0, IDX1, OUT1, X2G);
    knn2_kernel<<<dim3(256), dim3(512), 0, stream>>>(OUT1, X2G, IDX2);
    matmul128<<<dim3(512), dim3(256), 0, stream>>>(OUT1, Wq1, A0);
    matmul128<<<dim3(512), dim3(256), 0, stream>>>(OUT1, Wk1, A1);
    matmul128<<<dim3(512), dim3(256), 0, stream>>>(OUT1, Wv1, A2);
    matmul128<<<dim3(512), dim3(256), 0, stream>>>(OUT1, MK1, A3);
    matmul128<<<dim3(512), dim3(256), 0, stream>>>(OUT1, MV1, A4);
    attn_kernel<<<dim3(4096), dim3(256), 0, stream>>>(A0, A3, A1, A4, A2, BK1, BV1, IDX2, OUT1, nullptr);
    final_kernel<<<dim3(256), dim3(256), 0, stream>>>(tgt, OUT1, Wl, bl, g0, b0, g1, b1, out);
}

// Round 3
// 604.496 us; speedup vs baseline: 3.6344x; 1.3949x over previous
//
#include <hip/hip_runtime.h>
#include <math.h>

#define NB 4
#define NN 4096
#define NC 128
#define NROWS (NB*NN)
#define SCALE_F 0.08838834764831845f   // 1/sqrt(128)

using bf16x8 = __attribute__((ext_vector_type(8))) short;
using f32x4  = __attribute__((ext_vector_type(4))) float;

__device__ __forceinline__ float rl_f(float x, int l) {
    return __int_as_float(__builtin_amdgcn_readlane(__float_as_int(x), l));
}
__device__ __forceinline__ ushort f2bf(float x) {          // fp32 -> bf16 RNE
    unsigned u = __float_as_uint(x);
    return (ushort)((u + 0x7FFF + ((u >> 16) & 1)) >> 16);
}
__device__ __forceinline__ float bf2f(ushort b) { return __uint_as_float(((unsigned)b) << 16); }

// ---- 16-deep sorted (ascending) register lists, all named scalars ----
#define DECL16V \
    float v0=INFINITY,v1=INFINITY,v2=INFINITY,v3=INFINITY,v4=INFINITY,v5=INFINITY,v6=INFINITY,v7=INFINITY, \
          v8=INFINITY,v9=INFINITY,v10=INFINITY,v11=INFINITY,v12=INFINITY,v13=INFINITY,v14=INFINITY,v15=INFINITY;

#define DECL16I \
    int i0=0x7fffffff,i1=0x7fffffff,i2=0x7fffffff,i3=0x7fffffff,i4=0x7fffffff,i5=0x7fffffff,i6=0x7fffffff,i7=0x7fffffff, \
        i8=0x7fffffff,i9=0x7fffffff,i10=0x7fffffff,i11=0x7fffffff,i12=0x7fffffff,i13=0x7fffffff,i14=0x7fffffff,i15=0x7fffffff;

#define INSERT16V(dv) do { float d_=(dv); \
    bool m0=d_<v0,m1=d_<v1,m2=d_<v2,m3=d_<v3,m4=d_<v4,m5=d_<v5,m6=d_<v6,m7=d_<v7, \
         m8=d_<v8,m9=d_<v9,m10=d_<v10,m11=d_<v11,m12=d_<v12,m13=d_<v13,m14=d_<v14,m15=d_<v15; \
    v15=m14?v14:(m15?d_:v15); v14=m13?v13:(m14?d_:v14); v13=m12?v12:(m13?d_:v13); v12=m11?v11:(m12?d_:v12); \
    v11=m10?v10:(m11?d_:v11); v10=m9?v9:(m10?d_:v10); v9 =m8?v8:(m9?d_:v9);  v8 =m7?v7:(m8?d_:v8); \
    v7 =m6?v6:(m7?d_:v7);   v6 =m5?v5:(m6?d_:v6);   v5 =m4?v4:(m5?d_:v5);  v4 =m3?v3:(m4?d_:v4); \
    v3 =m2?v2:(m3?d_:v3);   v2 =m1?v1:(m2?d_:v2);   v1 =m0?v0:(m1?d_:v1);  v0 =m0?d_:v0; } while(0)

#define INSERT16VI(dv,jv) do { float d_=(dv); int j_=(jv); \
    bool m0=d_<v0,m1=d_<v1,m2=d_<v2,m3=d_<v3,m4=d_<v4,m5=d_<v5,m6=d_<v6,m7=d_<v7, \
         m8=d_<v8,m9=d_<v9,m10=d_<v10,m11=d_<v11,m12=d_<v12,m13=d_<v13,m14=d_<v14,m15=d_<v15; \
    v15=m14?v14:(m15?d_:v15); i15=m14?i14:(m15?j_:i15); \
    v14=m13?v13:(m14?d_:v14); i14=m13?i13:(m14?j_:i14); \
    v13=m12?v12:(m13?d_:v13); i13=m12?i12:(m13?j_:i13); \
    v12=m11?v11:(m12?d_:v12); i12=m11?i11:(m12?j_:i12); \
    v11=m10?v10:(m11?d_:v11); i11=m10?i10:(m11?j_:i11); \
    v10=m9?v9:(m10?d_:v10);   i10=m9?i9:(m10?j_:i10); \
    v9 =m8?v8:(m9?d_:v9);     i9 =m8?i8:(m9?j_:i9); \
    v8 =m7?v7:(m8?d_:v8);     i8 =m7?i7:(m8?j_:i8); \
    v7 =m6?v6:(m7?d_:v7);     i7 =m6?i6:(m7?j_:i7); \
    v6 =m5?v5:(m6?d_:v6);     i6 =m5?i5:(m6?j_:i6); \
    v5 =m4?v4:(m5?d_:v5);     i5 =m4?i4:(m5?j_:i5); \
    v4 =m3?v3:(m4?d_:v4);     i4 =m3?i3:(m4?j_:i4); \
    v3 =m2?v2:(m3?d_:v3);     i3 =m2?i2:(m3?j_:i3); \
    v2 =m1?v1:(m2?d_:v2);     i2 =m1?i1:(m2?j_:i2); \
    v1 =m0?v0:(m1?d_:v1);     i1 =m0?i0:(m1?j_:i1); \
    v0 =m0?d_:v0;             i0 =m0?j_:i0; } while(0)

#define POP16V(p) do { bool p_=(p); \
    v0=p_?v1:v0; v1=p_?v2:v1; v2=p_?v3:v2; v3=p_?v4:v3; v4=p_?v5:v4; v5=p_?v6:v5; v6=p_?v7:v6; v7=p_?v8:v7; \
    v8=p_?v9:v8; v9=p_?v10:v9; v10=p_?v11:v10; v11=p_?v12:v11; v12=p_?v13:v12; v13=p_?v14:v13; v14=p_?v15:v14; \
    v15=p_?INFINITY:v15; } while(0)

#define POP16VI(p) do { bool p_=(p); \
    v0=p_?v1:v0; i0=p_?i1:i0; v1=p_?v2:v1; i1=p_?i2:i1; v2=p_?v3:v2; i2=p_?i3:i2; v3=p_?v4:v3; i3=p_?i4:i3; \
    v4=p_?v5:v4; i4=p_?i5:i4; v5=p_?v6:v5; i5=p_?i6:i5; v6=p_?v7:v6; i6=p_?i7:i6; v7=p_?v8:v7; i7=p_?i8:i7; \
    v8=p_?v9:v8; i8=p_?i9:i8; v9=p_?v10:v9; i9=p_?i10:i9; v10=p_?v11:v10; i10=p_?i11:i10; \
    v11=p_?v12:v11; i11=p_?i12:i11; v12=p_?v13:v12; i12=p_?i13:i12; v13=p_?v14:v13; i13=p_?i14:i13; \
    v14=p_?v15:v14; i14=p_?i15:i14; v15=p_?INFINITY:v15; i15=p_?0x7fffffff:i15; } while(0)

// ---------------- tiny weight combos ----------------
__global__ void combo_small(const float* __restrict__ Wk0, const float* __restrict__ Wv0,
                            const float* __restrict__ Wp0, const float* __restrict__ bp0,
                            float* __restrict__ WKP0, float* __restrict__ BK0,
                            float* __restrict__ WVP0, float* __restrict__ BV0)
{
    int task = blockIdx.x * 512 + threadIdx.x;
    if (task >= 1024) return;
    int mat = task >> 9; int rem = task & 511;
    int c = rem >> 2, t = rem & 3;
    const float* W = mat ? Wv0 : Wk0;
    float s = 0.f;
    if (t < 3) {
        for (int d = 0; d < 128; ++d) s = fmaf(W[c*128+d], Wp0[d*3+t], s);
        (mat ? WVP0 : WKP0)[c*3+t] = s;
    } else {
        for (int d = 0; d < 128; ++d) s = fmaf(W[c*128+d], bp0[d], s);
        (mat ? BV0 : BK0)[c] = s;
    }
}

__global__ void combo_big(const float* __restrict__ Wk1, const float* __restrict__ Wv1,
                          const float* __restrict__ Wp1, const float* __restrict__ bp1,
                          float* __restrict__ MK1, float* __restrict__ BK1,
                          float* __restrict__ MV1, float* __restrict__ BV1)
{
    int task = blockIdx.x * 256 + threadIdx.x;
    if (task >= 33024) return;
    int mat = task >= 16512; int rem = mat ? task - 16512 : task;
    const float* W = mat ? Wv1 : Wk1;
    if (rem < 16384) {
        int c = rem >> 7, t = rem & 127;
        float s = 0.f;
        for (int d = 0; d < 128; ++d) s = fmaf(W[c*128+d], Wp1[d*128+t], s);
        (mat ? MV1 : MK1)[rem] = s;
    } else {
        int c = rem - 16384;
        float s = 0.f;
        for (int d = 0; d < 128; ++d) s = fmaf(W[c*128+d], bp1[d], s);
        (mat ? BV1 : BK1)[c] = s;
    }
}

__global__ void srcproj(const float* __restrict__ src, const float* __restrict__ WKP0,
                        const float* __restrict__ WVP0,
                        float* __restrict__ srcKp, float* __restrict__ srcVp)
{
    int gid = blockIdx.x * 256 + threadIdx.x;
    int i = gid >> 7, c = gid & 127;
    float s0 = src[i*3+0], s1 = src[i*3+1], s2 = src[i*3+2];
    srcKp[gid] = fmaf(s0, WKP0[c*3+0], fmaf(s1, WKP0[c*3+1], s2*WKP0[c*3+2]));
    srcVp[gid] = fmaf(s0, WVP0[c*3+0], fmaf(s1, WVP0[c*3+1], s2*WVP0[c*3+2]));
}

// ---------------- KNN stage 1 (3-D), one wave per row, value-threshold 2-pass ----------------
__global__ __launch_bounds__(256) void knn1_kernel(const float* __restrict__ src,
                                                   int* __restrict__ idxout)
{
    int lane = threadIdx.x & 63, wave = threadIdx.x >> 6;
    int b7 = blockIdx.x & 7, sub = blockIdx.x >> 3;
    int batch = b7 >> 1;
    int rib = (sub*2 + (b7 & 1))*4 + wave;
    int row = batch*NN + rib;
    const float* sb = src + batch*NN*3;
    float xi0 = sb[rib*3], xi1 = sb[rib*3+1], xi2 = sb[rib*3+2];

    DECL16V
    for (int it = 0; it < 64; ++it) {
        int j = it*64 + lane;
        float dx = xi0 - sb[j*3], dy = xi1 - sb[j*3+1], dz = xi2 - sb[j*3+2];
        float d2 = fmaf(dx, dx, fmaf(dy, dy, dz*dz));
        if (d2 < v15) INSERT16V(d2);
    }
    float T = INFINITY;
    for (int t = 0; t < 16; ++t) {
        float g = v0;
#pragma unroll
        for (int off = 1; off < 64; off <<= 1) g = fminf(g, __shfl_xor(g, off, 64));
        unsigned long long b = __ballot(v0 == g);
        int f = __ffsll((long long)b) - 1;
        POP16V(lane == f);
        T = g;
    }
    unsigned long long below_mask = (lane == 63) ? 0x7fffffffffffffffull : ((1ull << lane) - 1ull);
    int base = 0;
    for (int it = 0; it < 64; ++it) {
        int j = it*64 + lane;
        float dx = xi0 - sb[j*3], dy = xi1 - sb[j*3+1], dz = xi2 - sb[j*3+2];
        float d2 = fmaf(dx, dx, fmaf(dy, dy, dz*dz));
        unsigned long long blt = __ballot(d2 < T);
        if (d2 < T) idxout[row*16 + base + __popcll(blt & below_mask)] = j;
        base += __popcll(blt);
    }
    for (int it = 0; it < 64 && base < 16; ++it) {
        int j = it*64 + lane;
        float dx = xi0 - sb[j*3], dy = xi1 - sb[j*3+1], dz = xi2 - sb[j*3+2];
        float d2 = fmaf(dx, dx, fmaf(dy, dy, dz*dz));
        unsigned long long beq = __ballot(d2 == T);
        int bel = __popcll(beq & below_mask);
        if (d2 == T && base + bel < 16) idxout[row*16 + base + bel] = j;
        base += __popcll(beq);
    }
}

// ---------------- [M,128]@[128,128]^T matmul body (Y = X @ W^T) ----------------
__device__ __forceinline__ void matmul128_body(const float* __restrict__ X,
                                               const float* __restrict__ W,
                                               float* __restrict__ Y)
{
    __shared__ float WL[128*128];
    int tid = threadIdx.x;
    for (int f = tid; f < 16384; f += 256) {
        int c = f >> 7, d = f & 127;
        WL[d*128 + (c ^ (d & 14))] = W[f];
    }
    __syncthreads();
    int lane = tid & 63, wave = tid >> 6;
#pragma unroll
    for (int it = 0; it < 2; ++it) {
        int row0 = blockIdx.x*32 + it*16 + wave*4;
        float x0[4], x1[4];
#pragma unroll
        for (int r = 0; r < 4; ++r) {
            x0[r] = X[(row0+r)*128 + lane];
            x1[r] = X[(row0+r)*128 + lane + 64];
        }
        float2 acc[4];
#pragma unroll
        for (int r = 0; r < 4; ++r) { acc[r].x = 0.f; acc[r].y = 0.f; }
#pragma unroll 8
        for (int d = 0; d < 64; ++d) {
            int cidx = (2*lane) ^ (d & 14);
            float2 wa = *(const float2*)&WL[d*128 + cidx];
            float2 wb = *(const float2*)&WL[(d+64)*128 + cidx];
#pragma unroll
            for (int r = 0; r < 4; ++r) {
                float xa = rl_f(x0[r], d);
                float xb = rl_f(x1[r], d);
                acc[r].x = fmaf(xa, wa.x, acc[r].x);
                acc[r].y = fmaf(xa, wa.y, acc[r].y);
                acc[r].x = fmaf(xb, wb.x, acc[r].x);
                acc[r].y = fmaf(xb, wb.y, acc[r].y);
            }
        }
#pragma unroll
        for (int r = 0; r < 4; ++r) {
            *(float2*)&Y[(row0+r)*128 + 2*lane] = acc[r];
        }
    }
}

__global__ __launch_bounds__(256) void matmul128x3(
    const float* __restrict__ X,
    const float* __restrict__ W0, const float* __restrict__ W1, const float* __restrict__ W2,
    float* __restrict__ Y0, float* __restrict__ Y1, float* __restrict__ Y2)
{
    const float* W = (blockIdx.y == 0) ? W0 : ((blockIdx.y == 1) ? W1 : W2);
    float*       Y = (blockIdx.y == 0) ? Y0 : ((blockIdx.y == 1) ? Y1 : Y2);
    matmul128_body(X, W, Y);
}

__global__ __launch_bounds__(256) void matmul128x5(
    const float* __restrict__ X,
    const float* __restrict__ W0, const float* __restrict__ W1, const float* __restrict__ W2,
    const float* __restrict__ W3, const float* __restrict__ W4,
    float* __restrict__ Y0, float* __restrict__ Y1, float* __restrict__ Y2,
    float* __restrict__ Y3, float* __restrict__ Y4)
{
    const float* W; float* Y;
    switch (blockIdx.y) {
        case 0: W = W0; Y = Y0; break;
        case 1: W = W1; Y = Y1; break;
        case 2: W = W2; Y = Y2; break;
        case 3: W = W3; Y = Y3; break;
        default: W = W4; Y = Y4; break;
    }
    matmul128_body(X, W, Y);
}

// ---------------- gather attention (optionally emits bf16 hi/lo splits + x2) ----------------
__global__ __launch_bounds__(256) void attn_kernel(
    const float* __restrict__ Q,  const float* __restrict__ RK, const float* __restrict__ GK,
    const float* __restrict__ RV, const float* __restrict__ GV,
    const float* __restrict__ bk, const float* __restrict__ bv,
    const int* __restrict__ idx, float* __restrict__ outp, float* __restrict__ x2out,
    ushort* __restrict__ xh, ushort* __restrict__ xl)
{
    int lane = threadIdx.x & 63, wave = threadIdx.x >> 6;
    int b7 = blockIdx.x & 7, sub = blockIdx.x >> 3;
    int batch = b7 >> 1;
    int rib = (sub*2 + (b7 & 1))*4 + wave;
    int row = batch*NN + rib;
    const float* RKb = RK + (size_t)batch*NN*NC;
    const float* GKb = GK + (size_t)batch*NN*NC;
    const float* RVb = RV + (size_t)batch*NN*NC;
    const float* GVb = GV + (size_t)batch*NN*NC;

    float q0 = Q[row*NC + lane], q1 = Q[row*NC + lane + 64];
    float rki0 = RKb[rib*NC + lane], rki1 = RKb[rib*NC + lane + 64];
    float rvi0 = RVb[rib*NC + lane], rvi1 = RVb[rib*NC + lane + 64];
    float bka = bk[lane], bkb = bk[lane+64];
    float bva = bv[lane], bvb = bv[lane+64];

    int jarr[16];
#pragma unroll
    for (int k = 0; k < 16; ++k) jarr[k] = idx[row*16 + k];

    float sc[16];
#pragma unroll
    for (int k = 0; k < 16; ++k) {
        int j = jarr[k];
        float kk0 = rki0 - RKb[j*NC + lane]      + GKb[j*NC + lane]      + bka;
        float kk1 = rki1 - RKb[j*NC + lane + 64] + GKb[j*NC + lane + 64] + bkb;
        float p = fmaf(q0, kk0, q1*kk1);
#pragma unroll
        for (int off = 1; off < 64; off <<= 1) p += __shfl_xor(p, off, 64);
        sc[k] = p * SCALE_F;
    }
    float m = sc[0];
#pragma unroll
    for (int k = 1; k < 16; ++k) m = fmaxf(m, sc[k]);
    float wsum = 0.f, w[16];
#pragma unroll
    for (int k = 0; k < 16; ++k) { w[k] = expf(sc[k] - m); wsum += w[k]; }
    float inv = 1.f / wsum;
    float a0 = 0.f, a1 = 0.f;
#pragma unroll
    for (int k = 0; k < 16; ++k) {
        int j = jarr[k];
        float a = w[k] * inv;
        float vv0 = rvi0 - RVb[j*NC + lane]      + GVb[j*NC + lane]      + bva;
        float vv1 = rvi1 - RVb[j*NC + lane + 64] + GVb[j*NC + lane + 64] + bvb;
        a0 = fmaf(a, vv0, a0);
        a1 = fmaf(a, vv1, a1);
    }
    outp[row*NC + lane]      = a0;
    outp[row*NC + lane + 64] = a1;
    if (x2out != nullptr) {
        float x2 = fmaf(a0, a0, a1*a1);
#pragma unroll
        for (int off = 1; off < 64; off <<= 1) x2 += __shfl_xor(x2, off, 64);
        if (lane == 0) x2out[row] = x2;
    }
    if (xh != nullptr) {
        ushort h0 = f2bf(a0), h1 = f2bf(a1);
        xh[row*NC + lane]      = h0;
        xh[row*NC + lane + 64] = h1;
        xl[row*NC + lane]      = f2bf(a0 - bf2f(h0));
        xl[row*NC + lane + 64] = f2bf(a1 - bf2f(h1));
    }
}

// ---------------- KNN stage 2: split-bf16 MFMA Gram + register top-16 ----------------
// 64-row band/block, 128-col tiles, 8 waves. dot = hh + hl + lh + ll (fp32 accum).
// LDS 97 KiB: XCH/XCL swizzled bf16 col tiles, DT swizzled fp32 dot tile.
__global__ __launch_bounds__(512) void knn2_kernel(const ushort* __restrict__ XHg,
                                                   const ushort* __restrict__ XLg,
                                                   const float* __restrict__ x2g,
                                                   int* __restrict__ idxout)
{
    __shared__ __align__(16) ushort XCH[128*128];   // 32 KB [c][d ^ ((c&7)<<3)]
    __shared__ __align__(16) ushort XCL[128*128];   // 32 KB
    __shared__ __align__(16) float  DT[64*128];     // 32 KB [r][col ^ ((r&7)<<3)]
    __shared__ float X2T[2][128];                   // 1 KB double-buffered
    int tid = threadIdx.x;
    int lane = tid & 63, wave = tid >> 6;
    int xcd = blockIdx.x & 7, sub = blockIdx.x >> 3;     // grid 256
    int batch = xcd >> 1;
    int rowblk = sub*2 + (xcd & 1);
    const ushort* XHb = XHg + (size_t)batch*NN*NC;
    const ushort* XLb = XLg + (size_t)batch*NN*NC;
    const float*  x2b = x2g + (size_t)batch*NN;
    int r0 = rowblk*64;

    // A fragments (band rows) — invariant across col tiles, loaded once from global
    int rb = wave >> 1;                                  // wave's row block (16 rows)
    int dbase = (lane >> 4) * 8;
    int gr = r0 + rb*16 + (lane & 15);
    bf16x8 AH[4], AL[4];
#pragma unroll
    for (int ks = 0; ks < 4; ++ks) {
        AH[ks] = *(const bf16x8*)&XHb[(size_t)gr*NC + ks*32 + dbase];
        AL[ks] = *(const bf16x8*)&XLb[(size_t)gr*NC + ks*32 + dbase];
    }

    int srow = tid >> 3, slot = tid & 7;                 // scan: 8 threads per row
    DECL16V
    DECL16I

    for (int t = 0; t < 32; ++t) {
        int c0 = t*128;
        __syncthreads();                                 // DT(t-1) written; XC(t-1) consumed
        // stage col tile (hi,lo) with XOR swizzle
#pragma unroll
        for (int i = 0; i < 4; ++i) {
            int q = tid + 512*i;
            int c = q >> 4, d8 = q & 15;
            int widx = c*128 + ((d8*8) ^ ((c & 7) << 3));
            *(uint4*)&XCH[widx] = *(const uint4*)&XHb[(size_t)(c0 + c)*NC + d8*8];
            *(uint4*)&XCL[widx] = *(const uint4*)&XLb[(size_t)(c0 + c)*NC + d8*8];
        }
        if (tid < 128) X2T[t & 1][tid] = x2b[c0 + tid];
        // scan previous tile's dots
        if (t > 0) {
            int cp = c0 - 128;
            const float* x2s = X2T[(t-1) & 1];
#pragma unroll
            for (int k = 0; k < 16; ++k) {
                int col = slot + 8*k;
                float dot = DT[srow*128 + (col ^ ((srow & 7) << 3))];
                float d2 = fmaf(-2.f, dot, x2s[col]);
                if (d2 < v15) INSERT16VI(d2, cp + col);
            }
        }
        __syncthreads();                                 // staging visible; DT free
        // MFMA: wave computes 4 16x16 tiles (rb fixed, 4 col blocks)
        int cbBase = (wave & 1) * 4;
#pragma unroll
        for (int tt = 0; tt < 4; ++tt) {
            int cb = cbBase + tt;
            int cB = cb*16 + (lane & 15);
            f32x4 acc = {0.f, 0.f, 0.f, 0.f};
#pragma unroll
            for (int ks = 0; ks < 4; ++ks) {
                int bidx = cB*128 + ((ks*32 + dbase) ^ ((cB & 7) << 3));
                bf16x8 bh = *(const bf16x8*)&XCH[bidx];
                bf16x8 bl = *(const bf16x8*)&XCL[bidx];
                acc = __builtin_amdgcn_mfma_f32_16x16x32_bf16(AH[ks], bh, acc, 0, 0, 0);
                acc = __builtin_amdgcn_mfma_f32_16x16x32_bf16(AL[ks], bh, acc, 0, 0, 0);
                acc = __builtin_amdgcn_mfma_f32_16x16x32_bf16(AH[ks], bl, acc, 0, 0, 0);
                acc = __builtin_amdgcn_mfma_f32_16x16x32_bf16(AL[ks], bl, acc, 0, 0, 0);
            }
#pragma unroll
            for (int r2 = 0; r2 < 4; ++r2) {             // C/D: col=lane&15, row=(lane>>4)*4+reg
                int rA = rb*16 + (lane >> 4)*4 + r2;
                int col = cb*16 + (lane & 15);
                DT[rA*128 + (col ^ ((rA & 7) << 3))] = acc[r2];
            }
        }
    }
    __syncthreads();
    {   // scan last tile
        int cp = 31*128;
        const float* x2s = X2T[1];
#pragma unroll
        for (int k = 0; k < 16; ++k) {
            int col = slot + 8*k;
            float dot = DT[srow*128 + (col ^ ((srow & 7) << 3))];
            float d2 = fmaf(-2.f, dot, x2s[col]);
            if (d2 < v15) INSERT16VI(d2, cp + col);
        }
    }
    // merge the 8 per-thread lists of each row, lexicographic pop-merge
    int grow = batch*NN + r0 + srow;
    for (int t = 0; t < 16; ++t) {
        float gv = v0; int gi = i0;
#pragma unroll
        for (int off = 1; off < 8; off <<= 1) {
            float ov = __shfl_xor(gv, off, 64);
            int   oi = __shfl_xor(gi, off, 64);
            bool take = (ov < gv) || (ov == gv && oi < gi);
            gv = take ? ov : gv; gi = take ? oi : gi;
        }
        bool win = (v0 == gv) && (i0 == gi);
        if (win) idxout[grow*16 + t] = gi;
        POP16VI(win);
    }
}

// ---------------- final fused LN / linear / LN / transpose ----------------
__global__ __launch_bounds__(256) void final_kernel(
    const float* __restrict__ tgt, const float* __restrict__ att,
    const float* __restrict__ Wl, const float* __restrict__ bl,
    const float* __restrict__ g0, const float* __restrict__ b0,
    const float* __restrict__ g1, const float* __restrict__ b1,
    float* __restrict__ outp)
{
    __shared__ float WL[128*128];
    int tid = threadIdx.x;
    for (int f = tid; f < 16384; f += 256) {
        int c = f >> 7, d = f & 127;
        WL[d*128 + (c ^ (d & 14))] = Wl[f];
    }
    __syncthreads();
    int lane = tid & 63, wave = tid >> 6;
    float2 gg0 = *(const float2*)&g0[2*lane];
    float2 bb0 = *(const float2*)&b0[2*lane];
    float2 gg1 = *(const float2*)&g1[2*lane];
    float2 bb1 = *(const float2*)&b1[2*lane];
    float2 bl2 = *(const float2*)&bl[2*lane];
    for (int it = 0; it < 4; ++it) {
        int row0 = blockIdx.x*64 + it*16 + wave*4;
        float2 tg[4];
        float lnx[4], lny[4];
#pragma unroll
        for (int r = 0; r < 4; ++r) {
            int row = row0 + r;
            tg[r] = *(const float2*)&tgt[row*128 + 2*lane];
            float2 at = *(const float2*)&att[row*128 + 2*lane];
            float ox = tg[r].x + at.x, oy = tg[r].y + at.y;
            float s = ox + oy;
#pragma unroll
            for (int off = 1; off < 64; off <<= 1) s += __shfl_xor(s, off, 64);
            float mu = s * (1.f/128.f);
            float dx = ox - mu, dy = oy - mu;
            float vv = fmaf(dx, dx, dy*dy);
#pragma unroll
            for (int off = 1; off < 64; off <<= 1) vv += __shfl_xor(vv, off, 64);
            float rstd = rsqrtf(vv * (1.f/128.f) + 1e-5f);
            lnx[r] = dx * rstd * gg0.x + bb0.x;
            lny[r] = dy * rstd * gg0.y + bb0.y;
        }
        float2 acc[4];
#pragma unroll
        for (int r = 0; r < 4; ++r) { acc[r].x = 0.f; acc[r].y = 0.f; }
#pragma unroll 8
        for (int dh = 0; dh < 64; ++dh) {
            int cidx = (2*lane) ^ ((2*dh) & 14);
            float2 wa = *(const float2*)&WL[(2*dh)*128 + cidx];
            float2 wb = *(const float2*)&WL[(2*dh+1)*128 + cidx];
#pragma unroll
            for (int r = 0; r < 4; ++r) {
                float xa = rl_f(lnx[r], dh);
                float xb = rl_f(lny[r], dh);
                acc[r].x = fmaf(xa, wa.x, acc[r].x);
                acc[r].y = fmaf(xa, wa.y, acc[r].y);
                acc[r].x = fmaf(xb, wb.x, acc[r].x);
                acc[r].y = fmaf(xb, wb.y, acc[r].y);
            }
        }
#pragma unroll
        for (int r = 0; r < 4; ++r) {
            int row = row0 + r;
            float zx = tg[r].x + acc[r].x + bl2.x;
            float zy = tg[r].y + acc[r].y + bl2.y;
            float s = zx + zy;
#pragma unroll
            for (int off = 1; off < 64; off <<= 1) s += __shfl_xor(s, off, 64);
            float mu = s * (1.f/128.f);
            float dx = zx - mu, dy = zy - mu;
            float vv = fmaf(dx, dx, dy*dy);
#pragma unroll
            for (int off = 1; off < 64; off <<= 1) vv += __shfl_xor(vv, off, 64);
            float rstd = rsqrtf(vv * (1.f/128.f) + 1e-5f);
            float2 res;
            res.x = dx * rstd * gg1.x + bb1.x;
            res.y = dy * rstd * gg1.y + bb1.y;
            int b = row >> 12, n = row & 4095;
            *(float2*)&outp[((size_t)n*NB + b)*128 + 2*lane] = res;
        }
    }
}

extern "C" void kernel_launch(void* const* d_in, const int* in_sizes, int n_in,
                              void* d_out, int out_size, void* d_ws, size_t ws_size,
                              hipStream_t stream)
{
    (void)in_sizes; (void)n_in; (void)out_size; (void)ws_size;
    const float* src = (const float*)d_in[0];
    const float* tgt = (const float*)d_in[1];
    const float* Wq0 = (const float*)d_in[2];
    const float* Wk0 = (const float*)d_in[3];
    const float* Wv0 = (const float*)d_in[4];
    const float* Wq1 = (const float*)d_in[5];
    const float* Wk1 = (const float*)d_in[6];
    const float* Wv1 = (const float*)d_in[7];
    const float* Wp0 = (const float*)d_in[8];
    const float* bp0 = (const float*)d_in[9];
    const float* Wp1 = (const float*)d_in[10];
    const float* bp1 = (const float*)d_in[11];
    const float* Wl  = (const float*)d_in[12];
    const float* bl  = (const float*)d_in[13];
    const float* g0  = (const float*)d_in[14];
    const float* b0  = (const float*)d_in[15];
    const float* g1  = (const float*)d_in[16];
    const float* b1  = (const float*)d_in[17];
    float* out = (float*)d_out;

    float* A0   = (float*)d_ws;
    float* A1   = A0 + 2097152;
    float* A2   = A1 + 2097152;
    float* A3   = A2 + 2097152;
    float* A4   = A3 + 2097152;
    float* OUT1 = A4 + 2097152;
    int*   IDX1 = (int*)(OUT1 + 2097152);
    int*   IDX2 = IDX1 + NROWS*16;
    float* X2G  = (float*)(IDX2 + NROWS*16);
    float* WKP0 = X2G + NROWS;
    float* BK0  = WKP0 + 384;
    float* WVP0 = BK0 + 128;
    float* BV0  = WVP0 + 384;
    float* MK1  = BV0 + 128;
    float* BK1  = MK1 + 16384;
    float* MV1  = BK1 + 128;
    float* BV1  = MV1 + 16384;
    ushort* XH  = (ushort*)(BV1 + 128);      // 4 MB
    ushort* XL  = XH + (size_t)NROWS*NC;     // 4 MB

    combo_small<<<dim3(2), dim3(512), 0, stream>>>(Wk0, Wv0, Wp0, bp0, WKP0, BK0, WVP0, BV0);
    combo_big<<<dim3(129), dim3(256), 0, stream>>>(Wk1, Wv1, Wp1, bp1, MK1, BK1, MV1, BV1);
    srcproj<<<dim3(8192), dim3(256), 0, stream>>>(src, WKP0, WVP0, A3, A4);
    knn1_kernel<<<dim3(4096), dim3(256), 0, stream>>>(src, IDX1);
    matmul128x3<<<dim3(512, 3), dim3(256), 0, stream>>>(tgt, Wq0, Wk0, Wv0, A0, A1, A2);
    attn_kernel<<<dim3(4096), dim3(256), 0, stream>>>(A0, A3, A1, A4, A2, BK0, BV0, IDX1, OUT1, X2G, XH, XL);
    knn2_kernel<<<dim3(256), dim3(512), 0, stream>>>(XH, XL, X2G, IDX2);
    matmul128x5<<<dim3(512, 5), dim3(256), 0, stream>>>(OUT1, Wq1, Wk1, Wv1, MK1, MV1, A0, A1, A2, A3, A4);
    attn_kernel<<<dim3(4096), dim3(256), 0, stream>>>(A0, A3, A1, A4, A2, BK1, BV1, IDX2, OUT1, nullptr, nullptr, nullptr);
    final_kernel<<<dim3(256), dim3(256), 0, stream>>>(tgt, OUT1, Wl, bl, g0, b0, g1, b1, out);
}

// Round 4
// 584.542 us; speedup vs baseline: 3.7585x; 1.0341x over previous
//
#include <hip/hip_runtime.h>
#include <math.h>

#define NB 4
#define NN 4096
#define NC 128
#define NROWS (NB*NN)
#define SCALE_F 0.08838834764831845f   // 1/sqrt(128)

using bf16x8 = __attribute__((ext_vector_type(8))) short;
using f32x4  = __attribute__((ext_vector_type(4))) float;

__device__ __forceinline__ float rl_f(float x, int l) {
    return __int_as_float(__builtin_amdgcn_readlane(__float_as_int(x), l));
}
__device__ __forceinline__ ushort f2bf(float x) {          // fp32 -> bf16 RNE
    unsigned u = __float_as_uint(x);
    return (ushort)((u + 0x7FFF + ((u >> 16) & 1)) >> 16);
}
__device__ __forceinline__ float bf2f(ushort b) { return __uint_as_float(((unsigned)b) << 16); }

// ---- 16-deep sorted (ascending) register lists, all named scalars ----
#define DECL16V \
    float v0=INFINITY,v1=INFINITY,v2=INFINITY,v3=INFINITY,v4=INFINITY,v5=INFINITY,v6=INFINITY,v7=INFINITY, \
          v8=INFINITY,v9=INFINITY,v10=INFINITY,v11=INFINITY,v12=INFINITY,v13=INFINITY,v14=INFINITY,v15=INFINITY;

#define DECL16I \
    int i0=0x7fffffff,i1=0x7fffffff,i2=0x7fffffff,i3=0x7fffffff,i4=0x7fffffff,i5=0x7fffffff,i6=0x7fffffff,i7=0x7fffffff, \
        i8=0x7fffffff,i9=0x7fffffff,i10=0x7fffffff,i11=0x7fffffff,i12=0x7fffffff,i13=0x7fffffff,i14=0x7fffffff,i15=0x7fffffff;

#define INSERT16V(dv) do { float d_=(dv); \
    bool m0=d_<v0,m1=d_<v1,m2=d_<v2,m3=d_<v3,m4=d_<v4,m5=d_<v5,m6=d_<v6,m7=d_<v7, \
         m8=d_<v8,m9=d_<v9,m10=d_<v10,m11=d_<v11,m12=d_<v12,m13=d_<v13,m14=d_<v14,m15=d_<v15; \
    v15=m14?v14:(m15?d_:v15); v14=m13?v13:(m14?d_:v14); v13=m12?v12:(m13?d_:v13); v12=m11?v11:(m12?d_:v12); \
    v11=m10?v10:(m11?d_:v11); v10=m9?v9:(m10?d_:v10); v9 =m8?v8:(m9?d_:v9);  v8 =m7?v7:(m8?d_:v8); \
    v7 =m6?v6:(m7?d_:v7);   v6 =m5?v5:(m6?d_:v6);   v5 =m4?v4:(m5?d_:v5);  v4 =m3?v3:(m4?d_:v4); \
    v3 =m2?v2:(m3?d_:v3);   v2 =m1?v1:(m2?d_:v2);   v1 =m0?v0:(m1?d_:v1);  v0 =m0?d_:v0; } while(0)

#define INSERT16VI(dv,jv) do { float d_=(dv); int j_=(jv); \
    bool m0=d_<v0,m1=d_<v1,m2=d_<v2,m3=d_<v3,m4=d_<v4,m5=d_<v5,m6=d_<v6,m7=d_<v7, \
         m8=d_<v8,m9=d_<v9,m10=d_<v10,m11=d_<v11,m12=d_<v12,m13=d_<v13,m14=d_<v14,m15=d_<v15; \
    v15=m14?v14:(m15?d_:v15); i15=m14?i14:(m15?j_:i15); \
    v14=m13?v13:(m14?d_:v14); i14=m13?i13:(m14?j_:i14); \
    v13=m12?v12:(m13?d_:v13); i13=m12?i12:(m13?j_:i13); \
    v12=m11?v11:(m12?d_:v12); i12=m11?i11:(m12?j_:i12); \
    v11=m10?v10:(m11?d_:v11); i11=m10?i10:(m11?j_:i11); \
    v10=m9?v9:(m10?d_:v10);   i10=m9?i9:(m10?j_:i10); \
    v9 =m8?v8:(m9?d_:v9);     i9 =m8?i8:(m9?j_:i9); \
    v8 =m7?v7:(m8?d_:v8);     i8 =m7?i7:(m8?j_:i8); \
    v7 =m6?v6:(m7?d_:v7);     i7 =m6?i6:(m7?j_:i7); \
    v6 =m5?v5:(m6?d_:v6);     i6 =m5?i5:(m6?j_:i6); \
    v5 =m4?v4:(m5?d_:v5);     i5 =m4?i4:(m5?j_:i5); \
    v4 =m3?v3:(m4?d_:v4);     i4 =m3?i3:(m4?j_:i4); \
    v3 =m2?v2:(m3?d_:v3);     i3 =m2?i2:(m3?j_:i3); \
    v2 =m1?v1:(m2?d_:v2);     i2 =m1?i1:(m2?j_:i2); \
    v1 =m0?v0:(m1?d_:v1);     i1 =m0?i0:(m1?j_:i1); \
    v0 =m0?d_:v0;             i0 =m0?j_:i0; } while(0)

#define POP16V(p) do { bool p_=(p); \
    v0=p_?v1:v0; v1=p_?v2:v1; v2=p_?v3:v2; v3=p_?v4:v3; v4=p_?v5:v4; v5=p_?v6:v5; v6=p_?v7:v6; v7=p_?v8:v7; \
    v8=p_?v9:v8; v9=p_?v10:v9; v10=p_?v11:v10; v11=p_?v12:v11; v12=p_?v13:v12; v13=p_?v14:v13; v14=p_?v15:v14; \
    v15=p_?INFINITY:v15; } while(0)

// ---------------- tiny weight combos ----------------
__global__ void combo_small(const float* __restrict__ Wk0, const float* __restrict__ Wv0,
                            const float* __restrict__ Wp0, const float* __restrict__ bp0,
                            float* __restrict__ WKP0, float* __restrict__ BK0,
                            float* __restrict__ WVP0, float* __restrict__ BV0)
{
    int task = blockIdx.x * 512 + threadIdx.x;
    if (task >= 1024) return;
    int mat = task >> 9; int rem = task & 511;
    int c = rem >> 2, t = rem & 3;
    const float* W = mat ? Wv0 : Wk0;
    float s = 0.f;
    if (t < 3) {
        for (int d = 0; d < 128; ++d) s = fmaf(W[c*128+d], Wp0[d*3+t], s);
        (mat ? WVP0 : WKP0)[c*3+t] = s;
    } else {
        for (int d = 0; d < 128; ++d) s = fmaf(W[c*128+d], bp0[d], s);
        (mat ? BV0 : BK0)[c] = s;
    }
}

// WKD = Wk1 - Wk1@Wp1 ; MV1 = Wv1@Wp1 ; WVD = Wv1 - MV1 ; BV1 = Wv1@bp1
__global__ void combo_big(const float* __restrict__ Wk1, const float* __restrict__ Wv1,
                          const float* __restrict__ Wp1, const float* __restrict__ bp1,
                          float* __restrict__ WKD, float* __restrict__ MV1,
                          float* __restrict__ WVD, float* __restrict__ BV1)
{
    int task = blockIdx.x * 256 + threadIdx.x;   // grid 129 x 256
    if (task >= 32896) return;
    if (task < 32768) {
        int mat = task >> 14; int rem = task & 16383;
        int c = rem >> 7, tcol = rem & 127;
        const float* W = mat ? Wv1 : Wk1;
        float s = 0.f;
        for (int d = 0; d < 128; ++d) s = fmaf(W[c*128+d], Wp1[d*128+tcol], s);
        if (mat) { MV1[rem] = s; WVD[rem] = Wv1[rem] - s; }
        else     { WKD[rem] = Wk1[rem] - s; }
    } else {
        int c = task - 32768;
        float s = 0.f;
        for (int d = 0; d < 128; ++d) s = fmaf(Wv1[c*128+d], bp1[d], s);
        BV1[c] = s;
    }
}

__global__ void srcproj(const float* __restrict__ src, const float* __restrict__ WKP0,
                        const float* __restrict__ WVP0,
                        float* __restrict__ srcKp, float* __restrict__ srcVp)
{
    int gid = blockIdx.x * 256 + threadIdx.x;
    int i = gid >> 7, c = gid & 127;
    float s0 = src[i*3+0], s1 = src[i*3+1], s2 = src[i*3+2];
    srcKp[gid] = fmaf(s0, WKP0[c*3+0], fmaf(s1, WKP0[c*3+1], s2*WKP0[c*3+2]));
    srcVp[gid] = fmaf(s0, WVP0[c*3+0], fmaf(s1, WVP0[c*3+1], s2*WVP0[c*3+2]));
}

// ---------------- KNN stage 1 (3-D), one wave per row, value-threshold 2-pass ----------------
__global__ __launch_bounds__(256) void knn1_kernel(const float* __restrict__ src,
                                                   int* __restrict__ idxout)
{
    int lane = threadIdx.x & 63, wave = threadIdx.x >> 6;
    int b7 = blockIdx.x & 7, sub = blockIdx.x >> 3;
    int batch = b7 >> 1;
    int rib = (sub*2 + (b7 & 1))*4 + wave;
    int row = batch*NN + rib;
    const float* sb = src + batch*NN*3;
    float xi0 = sb[rib*3], xi1 = sb[rib*3+1], xi2 = sb[rib*3+2];

    DECL16V
    for (int it = 0; it < 64; ++it) {
        int j = it*64 + lane;
        float dx = xi0 - sb[j*3], dy = xi1 - sb[j*3+1], dz = xi2 - sb[j*3+2];
        float d2 = fmaf(dx, dx, fmaf(dy, dy, dz*dz));
        if (d2 < v15) INSERT16V(d2);
    }
    float T = INFINITY;
    for (int t = 0; t < 16; ++t) {
        float g = v0;
#pragma unroll
        for (int off = 1; off < 64; off <<= 1) g = fminf(g, __shfl_xor(g, off, 64));
        unsigned long long b = __ballot(v0 == g);
        int f = __ffsll((long long)b) - 1;
        POP16V(lane == f);
        T = g;
    }
    unsigned long long below_mask = (lane == 63) ? 0x7fffffffffffffffull : ((1ull << lane) - 1ull);
    int base = 0;
    for (int it = 0; it < 64; ++it) {
        int j = it*64 + lane;
        float dx = xi0 - sb[j*3], dy = xi1 - sb[j*3+1], dz = xi2 - sb[j*3+2];
        float d2 = fmaf(dx, dx, fmaf(dy, dy, dz*dz));
        unsigned long long blt = __ballot(d2 < T);
        if (d2 < T) idxout[row*16 + base + __popcll(blt & below_mask)] = j;
        base += __popcll(blt);
    }
    for (int it = 0; it < 64 && base < 16; ++it) {
        int j = it*64 + lane;
        float dx = xi0 - sb[j*3], dy = xi1 - sb[j*3+1], dz = xi2 - sb[j*3+2];
        float d2 = fmaf(dx, dx, fmaf(dy, dy, dz*dz));
        unsigned long long beq = __ballot(d2 == T);
        int bel = __popcll(beq & below_mask);
        if (d2 == T && base + bel < 16) idxout[row*16 + base + bel] = j;
        base += __popcll(beq);
    }
}

// ---------------- [M,128]@[128,128]^T matmul body (Y = X @ W^T - S) ----------------
__device__ __forceinline__ void matmul128_body(const float* __restrict__ X,
                                               const float* __restrict__ W,
                                               const float* __restrict__ S,
                                               float* __restrict__ Y)
{
    __shared__ float WL[128*128];
    int tid = threadIdx.x;
    for (int f = tid; f < 16384; f += 256) {
        int c = f >> 7, d = f & 127;
        WL[d*128 + (c ^ (d & 14))] = W[f];
    }
    __syncthreads();
    int lane = tid & 63, wave = tid >> 6;
#pragma unroll
    for (int it = 0; it < 2; ++it) {
        int row0 = blockIdx.x*32 + it*16 + wave*4;
        float x0[4], x1[4];
#pragma unroll
        for (int r = 0; r < 4; ++r) {
            x0[r] = X[(row0+r)*128 + lane];
            x1[r] = X[(row0+r)*128 + lane + 64];
        }
        float2 acc[4];
#pragma unroll
        for (int r = 0; r < 4; ++r) { acc[r].x = 0.f; acc[r].y = 0.f; }
#pragma unroll 8
        for (int d = 0; d < 64; ++d) {
            int cidx = (2*lane) ^ (d & 14);
            float2 wa = *(const float2*)&WL[d*128 + cidx];
            float2 wb = *(const float2*)&WL[(d+64)*128 + cidx];
#pragma unroll
            for (int r = 0; r < 4; ++r) {
                float xa = rl_f(x0[r], d);
                float xb = rl_f(x1[r], d);
                acc[r].x = fmaf(xa, wa.x, acc[r].x);
                acc[r].y = fmaf(xa, wa.y, acc[r].y);
                acc[r].x = fmaf(xb, wb.x, acc[r].x);
                acc[r].y = fmaf(xb, wb.y, acc[r].y);
            }
        }
#pragma unroll
        for (int r = 0; r < 4; ++r) {
            float2 o = acc[r];
            if (S != nullptr) {
                float2 s2 = *(const float2*)&S[(row0+r)*128 + 2*lane];
                o.x -= s2.x; o.y -= s2.y;
            }
            *(float2*)&Y[(row0+r)*128 + 2*lane] = o;
        }
    }
}

__global__ __launch_bounds__(256) void matmul128x3s(
    const float* __restrict__ X,
    const float* __restrict__ W0, const float* __restrict__ W1, const float* __restrict__ W2,
    const float* __restrict__ S1, const float* __restrict__ S2,
    float* __restrict__ Y0, float* __restrict__ Y1, float* __restrict__ Y2)
{
    if (blockIdx.y == 0)      matmul128_body(X, W0, nullptr, Y0);
    else if (blockIdx.y == 1) matmul128_body(X, W1, S1, Y1);
    else                      matmul128_body(X, W2, S2, Y2);
}

__global__ __launch_bounds__(256) void matmul128x4(
    const float* __restrict__ X,
    const float* __restrict__ W0, const float* __restrict__ W1,
    const float* __restrict__ W2, const float* __restrict__ W3,
    float* __restrict__ Y0, float* __restrict__ Y1,
    float* __restrict__ Y2, float* __restrict__ Y3)
{
    const float* W; float* Y;
    switch (blockIdx.y) {
        case 0: W = W0; Y = Y0; break;
        case 1: W = W1; Y = Y1; break;
        case 2: W = W2; Y = Y2; break;
        default: W = W3; Y = Y3; break;
    }
    matmul128_body(X, W, nullptr, Y);
}

// ---------------- gather attention (1 K-stream + 1 V-stream; softmax-shift-reduced) ----------------
// score_k = SCALE * q . GK[j_k] ; out = BASE[i] + bv + sum_k a_k GV[j_k]
__global__ __launch_bounds__(256) void attn_kernel(
    const float* __restrict__ Q,  const float* __restrict__ GK, const float* __restrict__ GV,
    const float* __restrict__ BASE, const float* __restrict__ bv,
    const int* __restrict__ idx, float* __restrict__ outp, float* __restrict__ x2out,
    ushort* __restrict__ xh, ushort* __restrict__ xl)
{
    int lane = threadIdx.x & 63, wave = threadIdx.x >> 6;
    int b7 = blockIdx.x & 7, sub = blockIdx.x >> 3;
    int batch = b7 >> 1;
    int rib = (sub*2 + (b7 & 1))*4 + wave;
    int row = batch*NN + rib;
    const float* GKb = GK + (size_t)batch*NN*NC;
    const float* GVb = GV + (size_t)batch*NN*NC;

    float q0 = Q[row*NC + lane], q1 = Q[row*NC + lane + 64];

    int jarr[16];
#pragma unroll
    for (int k = 0; k < 16; ++k) jarr[k] = idx[row*16 + k];

    float sc[16];
#pragma unroll
    for (int k = 0; k < 16; ++k) {
        int j = jarr[k];
        float p = fmaf(q0, GKb[j*NC + lane], q1*GKb[j*NC + lane + 64]);
#pragma unroll
        for (int off = 1; off < 64; off <<= 1) p += __shfl_xor(p, off, 64);
        sc[k] = p * SCALE_F;
    }
    float m = sc[0];
#pragma unroll
    for (int k = 1; k < 16; ++k) m = fmaxf(m, sc[k]);
    float wsum = 0.f, w[16];
#pragma unroll
    for (int k = 0; k < 16; ++k) { w[k] = expf(sc[k] - m); wsum += w[k]; }
    float inv = 1.f / wsum;
    float a0 = 0.f, a1 = 0.f;
#pragma unroll
    for (int k = 0; k < 16; ++k) {
        int j = jarr[k];
        float a = w[k] * inv;
        a0 = fmaf(a, GVb[j*NC + lane],      a0);
        a1 = fmaf(a, GVb[j*NC + lane + 64], a1);
    }
    a0 += BASE[row*NC + lane]      + bv[lane];
    a1 += BASE[row*NC + lane + 64] + bv[lane + 64];
    outp[row*NC + lane]      = a0;
    outp[row*NC + lane + 64] = a1;
    if (x2out != nullptr) {
        float x2 = fmaf(a0, a0, a1*a1);
#pragma unroll
        for (int off = 1; off < 64; off <<= 1) x2 += __shfl_xor(x2, off, 64);
        if (lane == 0) x2out[row] = x2;
    }
    if (xh != nullptr) {
        ushort h0 = f2bf(a0), h1 = f2bf(a1);
        xh[row*NC + lane]      = h0;
        xh[row*NC + lane + 64] = h1;
        xl[row*NC + lane]      = f2bf(a0 - bf2f(h0));
        xl[row*NC + lane + 64] = f2bf(a1 - bf2f(h1));
    }
}

// ---------------- KNN stage 2: split-bf16 MFMA Gram + queue-compacted owner top-16 ----------------
// 64-row band/block, 128-col tiles, 8 waves. One exact top-16 list per row (owner lane = slot 0),
// fed by ballot-compacted survivor queues gated on the owner's live threshold.
#define SCAN_TILE(CP, X2S) do { \
    float Trow = TrowS[srow]; \
    _Pragma("unroll") \
    for (int sb = 0; sb < 4; ++sb) { \
        int cnt = 0; \
        float d2a[4]; bool pa[4]; \
        _Pragma("unroll") \
        for (int q = 0; q < 4; ++q) { \
            int col = slot + 8*(sb*4 + q); \
            float dot = DT[srow*128 + (col ^ ((srow & 7) << 3))]; \
            d2a[q] = fmaf(-2.f, dot, (X2S)[col]); \
            pa[q] = d2a[q] <= Trow; \
        } \
        if (__ballot(pa[0] | pa[1] | pa[2] | pa[3]) != 0ull) { \
            _Pragma("unroll") \
            for (int q = 0; q < 4; ++q) { \
                unsigned long long bal = __ballot(pa[q]); \
                unsigned grp = (unsigned)(bal >> gsh) & 0xffu; \
                if (pa[q]) { \
                    int pos = cnt + __popc(grp & lowmask); \
                    QQ[srow][pos] = make_float2(d2a[q], __int_as_float(slot + 8*(sb*4+q))); \
                } \
                cnt += __popc(grp); \
            } \
            int n = isOwner ? cnt : 0; \
            for (int qi = 0; qi < n; ++qi) { \
                float2 e = QQ[srow][qi]; \
                float dd = e.x; int cc = __float_as_int(e.y); \
                if (dd < v15) INSERT16VI(dd, (CP) + cc); \
            } \
            if (isOwner) TrowS[srow] = v15; \
            Trow = TrowS[srow]; \
        } \
    } \
} while (0)

__global__ __launch_bounds__(512) void knn2_kernel(const ushort* __restrict__ XHg,
                                                   const ushort* __restrict__ XLg,
                                                   const float* __restrict__ x2g,
                                                   int* __restrict__ idxout)
{
    __shared__ __align__(16) ushort XCH[128*128];   // 32 KB [c][d ^ ((c&7)<<3)]
    __shared__ __align__(16) ushort XCL[128*128];   // 32 KB
    __shared__ __align__(16) float  DT[64*128];     // 32 KB [r][col ^ ((r&7)<<3)]
    __shared__ float2 QQ[64][33];                   // 16.5 KB survivor queues (cap 32, pad 33)
    __shared__ float TrowS[64];
    __shared__ float X2T[2][128];
    int tid = threadIdx.x;
    int lane = tid & 63, wave = tid >> 6;
    int xcd = blockIdx.x & 7, sub = blockIdx.x >> 3;     // grid 256
    int batch = xcd >> 1;
    int rowblk = sub*2 + (xcd & 1);
    const ushort* XHb = XHg + (size_t)batch*NN*NC;
    const ushort* XLb = XLg + (size_t)batch*NN*NC;
    const float*  x2b = x2g + (size_t)batch*NN;
    int r0 = rowblk*64;

    // A fragments (band rows) — invariant across col tiles
    int rb = wave >> 1;
    int dbase = (lane >> 4) * 8;
    int gr = r0 + rb*16 + (lane & 15);
    bf16x8 AH[4], AL[4];
#pragma unroll
    for (int ks = 0; ks < 4; ++ks) {
        AH[ks] = *(const bf16x8*)&XHb[(size_t)gr*NC + ks*32 + dbase];
        AL[ks] = *(const bf16x8*)&XLb[(size_t)gr*NC + ks*32 + dbase];
    }

    int srow = tid >> 3, slot = tid & 7;
    int gsh = (lane >> 3) * 8;
    unsigned lowmask = (1u << (lane & 7)) - 1u;
    bool isOwner = (slot == 0);
    DECL16V
    DECL16I

    for (int t = 0; t < 32; ++t) {
        int c0 = t*128;
        __syncthreads();                                 // DT(t-1) ready; XC(t-1) consumed
        // stage col tile (hi,lo) with XOR swizzle
#pragma unroll
        for (int i = 0; i < 4; ++i) {
            int q = tid + 512*i;
            int c = q >> 4, d8 = q & 15;
            int widx = c*128 + ((d8*8) ^ ((c & 7) << 3));
            *(uint4*)&XCH[widx] = *(const uint4*)&XHb[(size_t)(c0 + c)*NC + d8*8];
            *(uint4*)&XCL[widx] = *(const uint4*)&XLb[(size_t)(c0 + c)*NC + d8*8];
        }
        if (tid < 128) X2T[t & 1][tid] = x2b[c0 + tid];
        if (t > 0) {
            const float* x2s = X2T[(t-1) & 1];
            int cp = c0 - 128;
            if (t == 1) {
                // seed Trow: 16th-smallest of cols 0..15 of tile 0 (= their max)
                float da = fmaf(-2.f, DT[srow*128 + ((slot)     ^ ((srow & 7) << 3))], x2s[slot]);
                float db = fmaf(-2.f, DT[srow*128 + ((slot + 8) ^ ((srow & 7) << 3))], x2s[slot + 8]);
                float mx = fmaxf(da, db);
                mx = fmaxf(mx, __shfl_xor(mx, 1, 64));
                mx = fmaxf(mx, __shfl_xor(mx, 2, 64));
                mx = fmaxf(mx, __shfl_xor(mx, 4, 64));
                if (isOwner) TrowS[srow] = mx;
            }
            SCAN_TILE(cp, x2s);
        }
        __syncthreads();                                 // staging visible; DT free
        // MFMA: wave computes 4 16x16 tiles
        int cbBase = (wave & 1) * 4;
#pragma unroll
        for (int tt = 0; tt < 4; ++tt) {
            int cb = cbBase + tt;
            int cB = cb*16 + (lane & 15);
            f32x4 acc = {0.f, 0.f, 0.f, 0.f};
#pragma unroll
            for (int ks = 0; ks < 4; ++ks) {
                int bidx = cB*128 + ((ks*32 + dbase) ^ ((cB & 7) << 3));
                bf16x8 bh = *(const bf16x8*)&XCH[bidx];
                bf16x8 bl = *(const bf16x8*)&XCL[bidx];
                acc = __builtin_amdgcn_mfma_f32_16x16x32_bf16(AH[ks], bh, acc, 0, 0, 0);
                acc = __builtin_amdgcn_mfma_f32_16x16x32_bf16(AL[ks], bh, acc, 0, 0, 0);
                acc = __builtin_amdgcn_mfma_f32_16x16x32_bf16(AH[ks], bl, acc, 0, 0, 0);
                acc = __builtin_amdgcn_mfma_f32_16x16x32_bf16(AL[ks], bl, acc, 0, 0, 0);
            }
#pragma unroll
            for (int r2 = 0; r2 < 4; ++r2) {             // C/D: col=lane&15, row=(lane>>4)*4+reg
                int rA = rb*16 + (lane >> 4)*4 + r2;
                int col = cb*16 + (lane & 15);
                DT[rA*128 + (col ^ ((rA & 7) << 3))] = acc[r2];
            }
        }
    }
    __syncthreads();
    {   // scan last tile
        const float* x2s = X2T[1];
        SCAN_TILE(31*128, x2s);
    }
    if (isOwner) {
        int grow = batch*NN + r0 + srow;
        int* o = &idxout[grow*16];
        o[0]=i0; o[1]=i1; o[2]=i2; o[3]=i3; o[4]=i4; o[5]=i5; o[6]=i6; o[7]=i7;
        o[8]=i8; o[9]=i9; o[10]=i10; o[11]=i11; o[12]=i12; o[13]=i13; o[14]=i14; o[15]=i15;
    }
}

// ---------------- final fused LN / linear / LN / transpose ----------------
__global__ __launch_bounds__(256) void final_kernel(
    const float* __restrict__ tgt, const float* __restrict__ att,
    const float* __restrict__ Wl, const float* __restrict__ bl,
    const float* __restrict__ g0, const float* __restrict__ b0,
    const float* __restrict__ g1, const float* __restrict__ b1,
    float* __restrict__ outp)
{
    __shared__ float WL[128*128];
    int tid = threadIdx.x;
    for (int f = tid; f < 16384; f += 256) {
        int c = f >> 7, d = f & 127;
        WL[d*128 + (c ^ (d & 14))] = Wl[f];
    }
    __syncthreads();
    int lane = tid & 63, wave = tid >> 6;
    float2 gg0 = *(const float2*)&g0[2*lane];
    float2 bb0 = *(const float2*)&b0[2*lane];
    float2 gg1 = *(const float2*)&g1[2*lane];
    float2 bb1 = *(const float2*)&b1[2*lane];
    float2 bl2 = *(const float2*)&bl[2*lane];
    for (int it = 0; it < 4; ++it) {
        int row0 = blockIdx.x*64 + it*16 + wave*4;
        float2 tg[4];
        float lnx[4], lny[4];
#pragma unroll
        for (int r = 0; r < 4; ++r) {
            int row = row0 + r;
            tg[r] = *(const float2*)&tgt[row*128 + 2*lane];
            float2 at = *(const float2*)&att[row*128 + 2*lane];
            float ox = tg[r].x + at.x, oy = tg[r].y + at.y;
            float s = ox + oy;
#pragma unroll
            for (int off = 1; off < 64; off <<= 1) s += __shfl_xor(s, off, 64);
            float mu = s * (1.f/128.f);
            float dx = ox - mu, dy = oy - mu;
            float vv = fmaf(dx, dx, dy*dy);
#pragma unroll
            for (int off = 1; off < 64; off <<= 1) vv += __shfl_xor(vv, off, 64);
            float rstd = rsqrtf(vv * (1.f/128.f) + 1e-5f);
            lnx[r] = dx * rstd * gg0.x + bb0.x;
            lny[r] = dy * rstd * gg0.y + bb0.y;
        }
        float2 acc[4];
#pragma unroll
        for (int r = 0; r < 4; ++r) { acc[r].x = 0.f; acc[r].y = 0.f; }
#pragma unroll 8
        for (int dh = 0; dh < 64; ++dh) {
            int cidx = (2*lane) ^ ((2*dh) & 14);
            float2 wa = *(const float2*)&WL[(2*dh)*128 + cidx];
            float2 wb = *(const float2*)&WL[(2*dh+1)*128 + cidx];
#pragma unroll
            for (int r = 0; r < 4; ++r) {
                float xa = rl_f(lnx[r], dh);
                float xb = rl_f(lny[r], dh);
                acc[r].x = fmaf(xa, wa.x, acc[r].x);
                acc[r].y = fmaf(xa, wa.y, acc[r].y);
                acc[r].x = fmaf(xb, wb.x, acc[r].x);
                acc[r].y = fmaf(xb, wb.y, acc[r].y);
            }
        }
#pragma unroll
        for (int r = 0; r < 4; ++r) {
            int row = row0 + r;
            float zx = tg[r].x + acc[r].x + bl2.x;
            float zy = tg[r].y + acc[r].y + bl2.y;
            float s = zx + zy;
#pragma unroll
            for (int off = 1; off < 64; off <<= 1) s += __shfl_xor(s, off, 64);
            float mu = s * (1.f/128.f);
            float dx = zx - mu, dy = zy - mu;
            float vv = fmaf(dx, dx, dy*dy);
#pragma unroll
            for (int off = 1; off < 64; off <<= 1) vv += __shfl_xor(vv, off, 64);
            float rstd = rsqrtf(vv * (1.f/128.f) + 1e-5f);
            float2 res;
            res.x = dx * rstd * gg1.x + bb1.x;
            res.y = dy * rstd * gg1.y + bb1.y;
            int b = row >> 12, n = row & 4095;
            *(float2*)&outp[((size_t)n*NB + b)*128 + 2*lane] = res;
        }
    }
}

extern "C" void kernel_launch(void* const* d_in, const int* in_sizes, int n_in,
                              void* d_out, int out_size, void* d_ws, size_t ws_size,
                              hipStream_t stream)
{
    (void)in_sizes; (void)n_in; (void)out_size; (void)ws_size;
    const float* src = (const float*)d_in[0];
    const float* tgt = (const float*)d_in[1];
    const float* Wq0 = (const float*)d_in[2];
    const float* Wk0 = (const float*)d_in[3];
    const float* Wv0 = (const float*)d_in[4];
    const float* Wq1 = (const float*)d_in[5];
    const float* Wk1 = (const float*)d_in[6];
    const float* Wv1 = (const float*)d_in[7];
    const float* Wp0 = (const float*)d_in[8];
    const float* bp0 = (const float*)d_in[9];
    const float* Wp1 = (const float*)d_in[10];
    const float* bp1 = (const float*)d_in[11];
    const float* Wl  = (const float*)d_in[12];
    const float* bl  = (const float*)d_in[13];
    const float* g0  = (const float*)d_in[14];
    const float* b0  = (const float*)d_in[15];
    const float* g1  = (const float*)d_in[16];
    const float* b1  = (const float*)d_in[17];
    float* out = (float*)d_out;

    float* A0   = (float*)d_ws;
    float* A1   = A0 + 2097152;
    float* A2   = A1 + 2097152;
    float* A3   = A2 + 2097152;
    float* A4   = A3 + 2097152;
    float* OUT1 = A4 + 2097152;
    int*   IDX1 = (int*)(OUT1 + 2097152);
    int*   IDX2 = IDX1 + NROWS*16;
    float* X2G  = (float*)(IDX2 + NROWS*16);
    float* WKP0 = X2G + NROWS;
    float* BK0  = WKP0 + 384;
    float* WVP0 = BK0 + 128;
    float* BV0  = WVP0 + 384;
    float* WKD  = BV0 + 128;
    float* MV1  = WKD + 16384;
    float* WVD  = MV1 + 16384;
    float* BV1  = WVD + 16384;
    ushort* XH  = (ushort*)(BV1 + 128);      // 4 MB
    ushort* XL  = XH + (size_t)NROWS*NC;     // 4 MB

    combo_small<<<dim3(2), dim3(512), 0, stream>>>(Wk0, Wv0, Wp0, bp0, WKP0, BK0, WVP0, BV0);
    combo_big<<<dim3(129), dim3(256), 0, stream>>>(Wk1, Wv1, Wp1, bp1, WKD, MV1, WVD, BV1);
    srcproj<<<dim3(8192), dim3(256), 0, stream>>>(src, WKP0, WVP0, A3, A4);
    knn1_kernel<<<dim3(4096), dim3(256), 0, stream>>>(src, IDX1);
    // A0 = tgt@Wq0^T ; A1 = tgt@Wk0^T - srcKp ; A2 = tgt@Wv0^T - srcVp
    matmul128x3s<<<dim3(512, 3), dim3(256), 0, stream>>>(tgt, Wq0, Wk0, Wv0, A3, A4, A0, A1, A2);
    attn_kernel<<<dim3(4096), dim3(256), 0, stream>>>(A0, A1, A2, A4, BV0, IDX1, OUT1, X2G, XH, XL);
    knn2_kernel<<<dim3(256), dim3(512), 0, stream>>>(XH, XL, X2G, IDX2);
    // A0 = Q1 ; A1 = GK2 (W = Wk1 - Wk1Wp1) ; A2 = GV2 (W = Wv1 - Wv1Wp1) ; A3 = X@Mv1^T
    matmul128x4<<<dim3(512, 4), dim3(256), 0, stream>>>(OUT1, Wq1, WKD, WVD, MV1, A0, A1, A2, A3);
    attn_kernel<<<dim3(4096), dim3(256), 0, stream>>>(A0, A1, A2, A3, BV1, IDX2, OUT1, nullptr, nullptr, nullptr);
    final_kernel<<<dim3(256), dim3(256), 0, stream>>>(tgt, OUT1, Wl, bl, g0, b0, g1, b1, out);
}